// Round 7
// baseline (369.898 us; speedup 1.0000x reference)
//
#include <hip/hip_runtime.h>

// GCN: 2x GCNConv (5->16->32) + global mean pool + linear head.
// v6: CSR build with (src-half, dst) counting sort; layer-2 aggregation runs
// as two passes, each touching only a 3.2 MB half of the g table so the
// random gathers are per-XCD-L2-resident (same property that makes the
// layer-1 gather fast). Nontemporal hints keep streaming data from evicting
// the resident tables. No f32 atomics anywhere in aggregation.

#define NB 128            // dst buckets
#define RANGE 784         // nodes per bucket; NB*RANGE = 100352 >= N
#define NBR (NB * RANGE)
#define NKEY (2 * RANGE)  // (src-half, dst_local) keys per bucket
#define BINCHUNK 4096
#define PSPREAD 8

__global__ void k_hist(const int* __restrict__ dst, int E, int* __restrict__ bhist) {
    __shared__ int h[NB];
    for (int t = threadIdx.x; t < NB; t += blockDim.x) h[t] = 0;
    __syncthreads();
    for (int e = blockIdx.x * blockDim.x + threadIdx.x; e < E; e += gridDim.x * blockDim.x)
        atomicAdd(&h[__builtin_nontemporal_load(dst + e) / RANGE], 1);
    __syncthreads();
    for (int t = threadIdx.x; t < NB; t += blockDim.x)
        if (h[t]) atomicAdd(&bhist[t], h[t]);
}

__global__ void k_scan(const int* __restrict__ bhist, int* __restrict__ bbase,
                       int* __restrict__ bcursor) {
    __shared__ int s[NB];
    int t = threadIdx.x;  // NB threads
    int v = bhist[t];
    s[t] = v;
    __syncthreads();
    for (int off = 1; off < NB; off <<= 1) {
        int u = (t >= off) ? s[t - off] : 0;
        __syncthreads();
        s[t] += u;
        __syncthreads();
    }
    bbase[t] = s[t] - v;
    bcursor[t] = s[t] - v;
    if (t == NB - 1) bbase[NB] = s[t];
}

// bin edges into bucket-contiguous recbuf; rec = (src<<10) | dst_local
__global__ void k_bin(const int* __restrict__ src, const int* __restrict__ dst,
                      int* __restrict__ bcursor, unsigned int* __restrict__ recbuf, int E) {
    __shared__ int h[NB], h2[NB], base_l[NB];
    for (int t = threadIdx.x; t < NB; t += blockDim.x) { h[t] = 0; h2[t] = 0; }
    __syncthreads();
    int e0 = blockIdx.x * BINCHUNK;
    int e1 = min(e0 + BINCHUNK, E);
    for (int e = e0 + threadIdx.x; e < e1; e += blockDim.x)
        atomicAdd(&h[__builtin_nontemporal_load(dst + e) / RANGE], 1);
    __syncthreads();
    for (int t = threadIdx.x; t < NB; t += blockDim.x)
        base_l[t] = h[t] ? atomicAdd(&bcursor[t], h[t]) : 0;
    __syncthreads();
    for (int e = e0 + threadIdx.x; e < e1; e += blockDim.x) {
        int d = __builtin_nontemporal_load(dst + e);
        int s = __builtin_nontemporal_load(src + e);
        int b = d / RANGE;
        int rank = atomicAdd(&h2[b], 1);
        recbuf[base_l[b] + rank] = ((unsigned)s << 10) | (unsigned)(d - b * RANGE);
    }
}

// per-bucket LDS counting sort, key = (src>=Nhalf)*RANGE + dst_local.
// rp2[b*NKEY + key] = run starts; srt = src ids grouped by (half, dst).
__global__ __launch_bounds__(512) void k_sort(const int* __restrict__ bbase,
        const unsigned int* __restrict__ recbuf, int* __restrict__ rp2,
        int* __restrict__ srt, int Nhalf) {
    __shared__ int cnt[NKEY], lbase[NKEY], rank[NKEY];
    __shared__ int sc[2048];
    int b = blockIdx.x;
    int t = threadIdx.x;
    for (int i = t; i < NKEY; i += 512) { cnt[i] = 0; rank[i] = 0; }
    __syncthreads();
    int s0 = bbase[b], s1 = bbase[b + 1];
    for (int r = s0 + t; r < s1; r += 512) {
        unsigned rec = __builtin_nontemporal_load(recbuf + r);
        int key = ((int)(rec >> 10) >= Nhalf ? RANGE : 0) + (int)(rec & 1023);
        atomicAdd(&cnt[key], 1);
    }
    __syncthreads();
    for (int i = t; i < 2048; i += 512) sc[i] = (i < NKEY) ? cnt[i] : 0;
    __syncthreads();
    for (int off = 1; off < 2048; off <<= 1) {
        int i0 = t, i1 = t + 512, i2 = t + 1024, i3 = t + 1536;
        int a0 = (i0 >= off) ? sc[i0 - off] : 0;
        int a1 = (i1 >= off) ? sc[i1 - off] : 0;
        int a2 = (i2 >= off) ? sc[i2 - off] : 0;
        int a3 = (i3 >= off) ? sc[i3 - off] : 0;
        __syncthreads();
        sc[i0] += a0; sc[i1] += a1; sc[i2] += a2; sc[i3] += a3;
        __syncthreads();
    }
    for (int i = t; i < NKEY; i += 512) {
        lbase[i] = sc[i] - cnt[i];
        rp2[b * NKEY + i] = s0 + lbase[i];
    }
    if (b == NB - 1 && t == 0) rp2[NB * NKEY] = s1;
    __syncthreads();
    for (int r = s0 + t; r < s1; r += 512) {
        unsigned rec = __builtin_nontemporal_load(recbuf + r);
        int srcv = (int)(rec >> 10);
        int key = (srcv >= Nhalf ? RANGE : 0) + (int)(rec & 1023);
        int pos = s0 + lbase[key] + atomicAdd(&rank[key], 1);
        __builtin_nontemporal_store(srcv, srt + pos);
    }
}

// dinv = rsqrt(deg+1) from rp2; sx8 = [dinv*x (5), 0,0,0]
__global__ void k_prep(const float* __restrict__ x, const int* __restrict__ rp2,
                       float* __restrict__ dinv, float* __restrict__ sx8, int N) {
    int i = blockIdx.x * blockDim.x + threadIdx.x;
    if (i >= N) return;
    int b = i / RANGE, dl = i - b * RANGE;
    int base = b * NKEY + dl;
    int degA = rp2[base + 1] - rp2[base];
    int degB = rp2[base + RANGE + 1] - rp2[base + RANGE];
    float di = rsqrtf((float)(degA + degB + 1));
    dinv[i] = di;
    float4 a, bb;
    a.x = x[i * 5 + 0] * di; a.y = x[i * 5 + 1] * di;
    a.z = x[i * 5 + 2] * di; a.w = x[i * 5 + 3] * di;
    bb.x = x[i * 5 + 4] * di; bb.y = 0.f; bb.z = 0.f; bb.w = 0.f;
    float4* p = (float4*)(sx8 + (size_t)i * 8);
    p[0] = a; p[1] = bb;
}

// one wave per node; 8 feature lanes x 8 row slots; walks both A and B runs
__global__ void k_gather8(const int* __restrict__ rp2, const int* __restrict__ srt,
                          const float* __restrict__ sx8, float* __restrict__ agg8, int N) {
    int wid = (blockIdx.x * blockDim.x + threadIdx.x) >> 6;
    int lane = threadIdx.x & 63;
    if (wid >= N) return;
    int k = lane & 7, j = lane >> 3;
    int b = wid / RANGE, dl = wid - b * RANGE;
    int base = b * NKEY + dl;
    int pA0 = rp2[base], pA1 = rp2[base + 1];
    int pB0 = rp2[base + RANGE], pB1 = rp2[base + RANGE + 1];
    float acc = 0.f;
    for (int p = pA0 + j; p < pA1; p += 8)
        acc += sx8[(size_t)__builtin_nontemporal_load(srt + p) * 8 + k];
    for (int p = pB0 + j; p < pB1; p += 8)
        acc += sx8[(size_t)__builtin_nontemporal_load(srt + p) * 8 + k];
    acc += __shfl_xor(acc, 8, 64);
    acc += __shfl_xor(acc, 16, 64);
    acc += __shfl_xor(acc, 32, 64);
    if (lane < 8) agg8[(size_t)wid * 8 + k] = acc + sx8[(size_t)wid * 8 + k];
}

// h1 = relu(dinv*(agg8[:5]@W1) + b1); g = dinv*h1 (16); agg16 init = g (self)
__global__ void k_lin1(const float* __restrict__ agg8, const float* __restrict__ dinv,
                       const float* __restrict__ W1, const float* __restrict__ b1,
                       float* __restrict__ g, float* __restrict__ agg16, int N) {
    __shared__ float sW[80], sb[16];
    if (threadIdx.x < 80) sW[threadIdx.x] = W1[threadIdx.x];
    if (threadIdx.x < 16) sb[threadIdx.x] = b1[threadIdx.x];
    __syncthreads();
    int i = blockIdx.x * blockDim.x + threadIdx.x;
    if (i >= N) return;
    float di = dinv[i];
    const float4* a4 = (const float4*)(agg8 + (size_t)i * 8);
    float4 v0 = a4[0], v1 = a4[1];
    float a[5] = {v0.x, v0.y, v0.z, v0.w, v1.x};
    float4* g4 = (float4*)(g + (size_t)i * 16);
    float4* q4 = (float4*)(agg16 + (size_t)i * 16);
#pragma unroll
    for (int q = 0; q < 4; ++q) {
        float4 v;
        float* vp = (float*)&v;
#pragma unroll
        for (int r = 0; r < 4; ++r) {
            int kk = q * 4 + r;
            float h = 0.f;
#pragma unroll
            for (int d = 0; d < 5; ++d) h = fmaf(a[d], sW[d * 16 + kk], h);
            h = fmaxf(fmaf(di, h, sb[kk]), 0.f);
            vp[r] = h * di;
        }
        g4[q] = v;
        q4[q] = v;
    }
}

// one wave per node; 16 feature lanes x 4 row slots; processes ONE src-half
// run (hoff = 0 for src<Nhalf, RANGE for src>=Nhalf) and accumulates into
// agg16 (initialized to self by k_lin1). Table slice is L2-resident (3.2 MB).
__global__ void k_gath16h(const int* __restrict__ rp2, const int* __restrict__ srt,
                          const float* __restrict__ g, float* __restrict__ agg16,
                          int N, int hoff) {
    int wid = (blockIdx.x * blockDim.x + threadIdx.x) >> 6;
    int lane = threadIdx.x & 63;
    if (wid >= N) return;
    int k = lane & 15, j = lane >> 4;
    int b = wid / RANGE, dl = wid - b * RANGE;
    int base = b * NKEY + hoff + dl;
    int p0 = rp2[base], p1 = rp2[base + 1];
    float prev = 0.f;
    if (lane < 16) prev = agg16[(size_t)wid * 16 + k];
    float acc = 0.f;
    int p = p0 + j;
    for (; p + 4 < p1; p += 8) {
        int sA = __builtin_nontemporal_load(srt + p);
        int sB = __builtin_nontemporal_load(srt + p + 4);
        acc += g[(size_t)sA * 16 + k] + g[(size_t)sB * 16 + k];
    }
    for (; p < p1; p += 4) acc += g[(size_t)__builtin_nontemporal_load(srt + p) * 16 + k];
    acc += __shfl_xor(acc, 16, 64);
    acc += __shfl_xor(acc, 32, 64);
    if (lane < 16) agg16[(size_t)wid * 16 + k] = prev + acc;
}

// h2 = relu(dinv*(agg16@W2) + b2); c = h2 . fcW; spread-8 pool atomics
__global__ void k_fin(const float* __restrict__ agg16, const float* __restrict__ dinv,
                      const float* __restrict__ W2, const float* __restrict__ b2,
                      const float* __restrict__ fcW, const int* __restrict__ batch,
                      float* __restrict__ pool, int* __restrict__ gcnt, int N, int G) {
    __shared__ float sW[512], sb[32], sf[32];
    for (int t = threadIdx.x; t < 512; t += blockDim.x) sW[t] = W2[t];
    if (threadIdx.x < 32) {
        sb[threadIdx.x] = b2[threadIdx.x];
        sf[threadIdx.x] = fcW[threadIdx.x];
    }
    __syncthreads();
    int i = blockIdx.x * blockDim.x + threadIdx.x;
    if (i >= N) return;
    float di = dinv[i];
    float a[16];
    const float4* a4 = (const float4*)(agg16 + (size_t)i * 16);
#pragma unroll
    for (int q = 0; q < 4; ++q) {
        float4 v = a4[q];
        a[q * 4 + 0] = v.x; a[q * 4 + 1] = v.y; a[q * 4 + 2] = v.z; a[q * 4 + 3] = v.w;
    }
    float c = 0.f;
#pragma unroll
    for (int jj = 0; jj < 32; ++jj) {
        float acc2 = 0.f;
#pragma unroll
        for (int kk = 0; kk < 16; ++kk) acc2 = fmaf(a[kk], sW[kk * 32 + jj], acc2);
        float h = fmaxf(fmaf(di, acc2, sb[jj]), 0.f);
        c = fmaf(h, sf[jj], c);
    }
    int bidx = batch[i];
    int slot = i & (PSPREAD - 1);
    atomicAdd(&pool[slot * G + bidx], c);
    atomicAdd(&gcnt[slot * G + bidx], 1);
}

__global__ void k_out(const float* __restrict__ pool, const int* __restrict__ gcnt,
                      const float* __restrict__ fcb, float* __restrict__ out, int G) {
    int gI = blockIdx.x * blockDim.x + threadIdx.x;
    if (gI >= G) return;
    float s = 0.f; int c = 0;
#pragma unroll
    for (int k = 0; k < PSPREAD; ++k) { s += pool[k * G + gI]; c += gcnt[k * G + gI]; }
    out[gI] = s / fmaxf((float)c, 1.f) + fcb[0];
}

extern "C" void kernel_launch(void* const* d_in, const int* in_sizes, int n_in,
                              void* d_out, int out_size, void* d_ws, size_t ws_size,
                              hipStream_t stream) {
    const float* x    = (const float*)d_in[0];
    const int*   ei   = (const int*)d_in[1];
    const int*   batch= (const int*)d_in[2];
    const float* W1   = (const float*)d_in[3];
    const float* b1   = (const float*)d_in[4];
    const float* W2   = (const float*)d_in[5];
    const float* b2   = (const float*)d_in[6];
    const float* fcW  = (const float*)d_in[7];
    const float* fcb  = (const float*)d_in[8];
    float* out = (float*)d_out;

    const int N = in_sizes[0] / 5;
    const int E = in_sizes[1] / 2;
    const int G = out_size;  // 1024
    const int Nhalf = (N + 1) / 2;

    const int* src = ei;
    const int* dst = ei + E;

    // workspace carve (all offsets 16B-aligned)
    char* ws = (char*)d_ws;
    size_t o = 0;
    int*   bhist  = (int*)  (ws + o); o += 1024;
    int*   bbase  = (int*)  (ws + o); o += 1024;            // NB+1 ints
    int*   bcursor= (int*)  (ws + o); o += 1024;
    int*   rp2    = (int*)  (ws + o); o += (size_t)4 * (NB * NKEY + 4);
    float* dinv   = (float*)(ws + o); o += (size_t)4 * N;
    float* sx8    = (float*)(ws + o); o += (size_t)32 * N;
    float* agg8   = (float*)(ws + o); o += (size_t)32 * N;
    float* agg16  = (float*)(ws + o); o += (size_t)64 * N;
    int*   srt    = (int*)  (ws + o); o += (size_t)4 * E;
    unsigned int* recbuf = (unsigned int*)(ws + o);         // 4E, dead after k_sort
    float* g      = (float*)(ws + o); o += (size_t)4 * E;   // g (64N) aliases recbuf
    float* pool   = (float*)(ws + o); o += (size_t)4 * PSPREAD * G;
    int*   gcnt   = (int*)  (ws + o); o += (size_t)4 * PSPREAD * G;

    hipMemsetAsync(bhist, 0, 1024, stream);
    hipMemsetAsync(pool, 0, (size_t)8 * PSPREAD * G, stream);  // pool+gcnt contiguous

    k_hist<<<256, 256, 0, stream>>>(dst, E, bhist);
    k_scan<<<1, NB, 0, stream>>>(bhist, bbase, bcursor);
    k_bin<<<(E + BINCHUNK - 1) / BINCHUNK, 256, 0, stream>>>(src, dst, bcursor, recbuf, E);
    k_sort<<<NB, 512, 0, stream>>>(bbase, recbuf, rp2, srt, Nhalf);
    k_prep<<<(N + 255) / 256, 256, 0, stream>>>(x, rp2, dinv, sx8, N);
    {
        int blocks = (int)(((long long)N * 64 + 255) / 256);
        k_gather8<<<blocks, 256, 0, stream>>>(rp2, srt, sx8, agg8, N);
    }
    k_lin1<<<(N + 255) / 256, 256, 0, stream>>>(agg8, dinv, W1, b1, g, agg16, N);
    {
        int blocks = (int)(((long long)N * 64 + 255) / 256);
        k_gath16h<<<blocks, 256, 0, stream>>>(rp2, srt, g, agg16, N, 0);
        k_gath16h<<<blocks, 256, 0, stream>>>(rp2, srt, g, agg16, N, RANGE);
    }
    k_fin<<<(N + 255) / 256, 256, 0, stream>>>(agg16, dinv, W2, b2, fcW, batch, pool, gcnt, N, G);
    k_out<<<(G + 255) / 256, 256, 0, stream>>>(pool, gcnt, fcb, out, G);
}

// Round 8
// 316.474 us; speedup vs baseline: 1.1688x; 1.1688x over previous
//
#include <hip/hip_runtime.h>

// GCN: 2x GCNConv (5->16->32) + global mean pool + linear head.
// v7: CSR build with (src-half, dst) counting sort; layer-2 aggregation as two
// passes over 3.2 MB g-halves (per-XCD-L2-resident). vs v6: srt stores are
// PLAIN (v6's nontemporal scattered stores wrote through to HBM: 179 MB
// WRITE_SIZE on k_sort), and buckets are 256-wide (NB=391 blocks) so the
// sort occupies all CUs.

#define RANGE 256         // nodes per bucket (d>>8)
#define NB 391            // ceil(100000/256); N=100000 fixed by problem
#define NKEY (2 * RANGE)  // (src-half, dst_local) keys per bucket
#define BINCHUNK 4096
#define PSPREAD 8

__global__ void k_hist(const int* __restrict__ dst, int E, int* __restrict__ bhist) {
    __shared__ int h[NB];
    for (int t = threadIdx.x; t < NB; t += blockDim.x) h[t] = 0;
    __syncthreads();
    for (int e = blockIdx.x * blockDim.x + threadIdx.x; e < E; e += gridDim.x * blockDim.x)
        atomicAdd(&h[__builtin_nontemporal_load(dst + e) >> 8], 1);
    __syncthreads();
    for (int t = threadIdx.x; t < NB; t += blockDim.x)
        if (h[t]) atomicAdd(&bhist[t], h[t]);
}

// single block, 512 threads: exclusive scan of bhist[0..NB) -> bbase, bcursor
__global__ __launch_bounds__(512) void k_scan(const int* __restrict__ bhist,
        int* __restrict__ bbase, int* __restrict__ bcursor) {
    __shared__ int sc[512];
    int t = threadIdx.x;
    int v = (t < NB) ? bhist[t] : 0;
    sc[t] = v;
    __syncthreads();
    for (int off = 1; off < 512; off <<= 1) {
        int u = (t >= off) ? sc[t - off] : 0;
        __syncthreads();
        sc[t] += u;
        __syncthreads();
    }
    if (t < NB) {
        bbase[t] = sc[t] - v;
        bcursor[t] = sc[t] - v;
    }
    if (t == NB - 1) bbase[NB] = sc[t];
}

// bin edges into bucket-contiguous recbuf; rec = (src<<8) | dst_local
__global__ void k_bin(const int* __restrict__ src, const int* __restrict__ dst,
                      int* __restrict__ bcursor, unsigned int* __restrict__ recbuf, int E) {
    __shared__ int h[NB], h2[NB], base_l[NB];
    for (int t = threadIdx.x; t < NB; t += blockDim.x) { h[t] = 0; h2[t] = 0; }
    __syncthreads();
    int e0 = blockIdx.x * BINCHUNK;
    int e1 = min(e0 + BINCHUNK, E);
    for (int e = e0 + threadIdx.x; e < e1; e += blockDim.x)
        atomicAdd(&h[__builtin_nontemporal_load(dst + e) >> 8], 1);
    __syncthreads();
    for (int t = threadIdx.x; t < NB; t += blockDim.x)
        base_l[t] = h[t] ? atomicAdd(&bcursor[t], h[t]) : 0;
    __syncthreads();
    for (int e = e0 + threadIdx.x; e < e1; e += blockDim.x) {
        int d = __builtin_nontemporal_load(dst + e);
        int s = __builtin_nontemporal_load(src + e);
        int b = d >> 8;
        int rank = atomicAdd(&h2[b], 1);
        recbuf[base_l[b] + rank] = ((unsigned)s << 8) | (unsigned)(d & 255);
    }
}

// per-bucket LDS counting sort, key = (src>=Nhalf)*RANGE + dst_local.
// rp2[b*NKEY + key] = run starts (globally monotone); srt = src ids.
__global__ __launch_bounds__(512) void k_sort(const int* __restrict__ bbase,
        const unsigned int* __restrict__ recbuf, int* __restrict__ rp2,
        int* __restrict__ srt, int Nhalf) {
    __shared__ int cnt[NKEY], lbase[NKEY], rank[NKEY], sc[NKEY];
    int b = blockIdx.x;
    int t = threadIdx.x;
    cnt[t] = 0; rank[t] = 0;
    __syncthreads();
    int s0 = bbase[b], s1 = bbase[b + 1];
    for (int r = s0 + t; r < s1; r += 512) {
        unsigned rec = __builtin_nontemporal_load(recbuf + r);
        int key = ((int)(rec >> 8) >= Nhalf ? RANGE : 0) + (int)(rec & 255);
        atomicAdd(&cnt[key], 1);
    }
    __syncthreads();
    sc[t] = cnt[t];
    __syncthreads();
    for (int off = 1; off < NKEY; off <<= 1) {
        int u = (t >= off) ? sc[t - off] : 0;
        __syncthreads();
        sc[t] += u;
        __syncthreads();
    }
    lbase[t] = sc[t] - cnt[t];
    rp2[b * NKEY + t] = s0 + lbase[t];
    if (b == NB - 1 && t == 0) rp2[NB * NKEY] = s1;
    __syncthreads();
    for (int r = s0 + t; r < s1; r += 512) {
        unsigned rec = __builtin_nontemporal_load(recbuf + r);
        int srcv = (int)(rec >> 8);
        int key = (srcv >= Nhalf ? RANGE : 0) + (int)(rec & 255);
        int pos = s0 + lbase[key] + atomicAdd(&rank[key], 1);
        srt[pos] = srcv;   // plain store: L2-merged within bucket slice
    }
}

// dinv = rsqrt(deg+1) from rp2; sx8 = [dinv*x (5), 0,0,0]
__global__ void k_prep(const float* __restrict__ x, const int* __restrict__ rp2,
                       float* __restrict__ dinv, float* __restrict__ sx8, int N) {
    int i = blockIdx.x * blockDim.x + threadIdx.x;
    if (i >= N) return;
    int b = i >> 8, dl = i & 255;
    int base = b * NKEY + dl;
    int degA = rp2[base + 1] - rp2[base];
    int degB = rp2[base + RANGE + 1] - rp2[base + RANGE];
    float di = rsqrtf((float)(degA + degB + 1));
    dinv[i] = di;
    float4 a, bb;
    a.x = x[i * 5 + 0] * di; a.y = x[i * 5 + 1] * di;
    a.z = x[i * 5 + 2] * di; a.w = x[i * 5 + 3] * di;
    bb.x = x[i * 5 + 4] * di; bb.y = 0.f; bb.z = 0.f; bb.w = 0.f;
    float4* p = (float4*)(sx8 + (size_t)i * 8);
    p[0] = a; p[1] = bb;
}

// one wave per node; 8 feature lanes x 8 row slots; walks both A and B runs
__global__ void k_gather8(const int* __restrict__ rp2, const int* __restrict__ srt,
                          const float* __restrict__ sx8, float* __restrict__ agg8, int N) {
    int wid = (blockIdx.x * blockDim.x + threadIdx.x) >> 6;
    int lane = threadIdx.x & 63;
    if (wid >= N) return;
    int k = lane & 7, j = lane >> 3;
    int b = wid >> 8, dl = wid & 255;
    int base = b * NKEY + dl;
    int pA0 = rp2[base], pA1 = rp2[base + 1];
    int pB0 = rp2[base + RANGE], pB1 = rp2[base + RANGE + 1];
    float acc = 0.f;
    for (int p = pA0 + j; p < pA1; p += 8)
        acc += sx8[(size_t)__builtin_nontemporal_load(srt + p) * 8 + k];
    for (int p = pB0 + j; p < pB1; p += 8)
        acc += sx8[(size_t)__builtin_nontemporal_load(srt + p) * 8 + k];
    acc += __shfl_xor(acc, 8, 64);
    acc += __shfl_xor(acc, 16, 64);
    acc += __shfl_xor(acc, 32, 64);
    if (lane < 8) agg8[(size_t)wid * 8 + k] = acc + sx8[(size_t)wid * 8 + k];
}

// h1 = relu(dinv*(agg8[:5]@W1) + b1); g = dinv*h1 (16); agg16 init = g (self)
__global__ void k_lin1(const float* __restrict__ agg8, const float* __restrict__ dinv,
                       const float* __restrict__ W1, const float* __restrict__ b1,
                       float* __restrict__ g, float* __restrict__ agg16, int N) {
    __shared__ float sW[80], sb[16];
    if (threadIdx.x < 80) sW[threadIdx.x] = W1[threadIdx.x];
    if (threadIdx.x < 16) sb[threadIdx.x] = b1[threadIdx.x];
    __syncthreads();
    int i = blockIdx.x * blockDim.x + threadIdx.x;
    if (i >= N) return;
    float di = dinv[i];
    const float4* a4 = (const float4*)(agg8 + (size_t)i * 8);
    float4 v0 = a4[0], v1 = a4[1];
    float a[5] = {v0.x, v0.y, v0.z, v0.w, v1.x};
    float4* g4 = (float4*)(g + (size_t)i * 16);
    float4* q4 = (float4*)(agg16 + (size_t)i * 16);
#pragma unroll
    for (int q = 0; q < 4; ++q) {
        float4 v;
        float* vp = (float*)&v;
#pragma unroll
        for (int r = 0; r < 4; ++r) {
            int kk = q * 4 + r;
            float h = 0.f;
#pragma unroll
            for (int d = 0; d < 5; ++d) h = fmaf(a[d], sW[d * 16 + kk], h);
            h = fmaxf(fmaf(di, h, sb[kk]), 0.f);
            vp[r] = h * di;
        }
        g4[q] = v;
        q4[q] = v;
    }
}

// one wave per node; 16 feature lanes x 4 row slots; one src-half run
// (hoff = 0 or RANGE); accumulates into agg16 (self-initialized by k_lin1).
__global__ void k_gath16h(const int* __restrict__ rp2, const int* __restrict__ srt,
                          const float* __restrict__ g, float* __restrict__ agg16,
                          int N, int hoff) {
    int wid = (blockIdx.x * blockDim.x + threadIdx.x) >> 6;
    int lane = threadIdx.x & 63;
    if (wid >= N) return;
    int k = lane & 15, j = lane >> 4;
    int b = wid >> 8, dl = wid & 255;
    int base = b * NKEY + hoff + dl;
    int p0 = rp2[base], p1 = rp2[base + 1];
    float prev = 0.f;
    if (lane < 16) prev = agg16[(size_t)wid * 16 + k];
    float acc = 0.f;
    int p = p0 + j;
    for (; p + 4 < p1; p += 8) {
        int sA = __builtin_nontemporal_load(srt + p);
        int sB = __builtin_nontemporal_load(srt + p + 4);
        acc += g[(size_t)sA * 16 + k] + g[(size_t)sB * 16 + k];
    }
    for (; p < p1; p += 4) acc += g[(size_t)__builtin_nontemporal_load(srt + p) * 16 + k];
    acc += __shfl_xor(acc, 16, 64);
    acc += __shfl_xor(acc, 32, 64);
    if (lane < 16) agg16[(size_t)wid * 16 + k] = prev + acc;
}

// h2 = relu(dinv*(agg16@W2) + b2); c = h2 . fcW; spread-8 pool atomics
__global__ void k_fin(const float* __restrict__ agg16, const float* __restrict__ dinv,
                      const float* __restrict__ W2, const float* __restrict__ b2,
                      const float* __restrict__ fcW, const int* __restrict__ batch,
                      float* __restrict__ pool, int* __restrict__ gcnt, int N, int G) {
    __shared__ float sW[512], sb[32], sf[32];
    for (int t = threadIdx.x; t < 512; t += blockDim.x) sW[t] = W2[t];
    if (threadIdx.x < 32) {
        sb[threadIdx.x] = b2[threadIdx.x];
        sf[threadIdx.x] = fcW[threadIdx.x];
    }
    __syncthreads();
    int i = blockIdx.x * blockDim.x + threadIdx.x;
    if (i >= N) return;
    float di = dinv[i];
    float a[16];
    const float4* a4 = (const float4*)(agg16 + (size_t)i * 16);
#pragma unroll
    for (int q = 0; q < 4; ++q) {
        float4 v = a4[q];
        a[q * 4 + 0] = v.x; a[q * 4 + 1] = v.y; a[q * 4 + 2] = v.z; a[q * 4 + 3] = v.w;
    }
    float c = 0.f;
#pragma unroll
    for (int jj = 0; jj < 32; ++jj) {
        float acc2 = 0.f;
#pragma unroll
        for (int kk = 0; kk < 16; ++kk) acc2 = fmaf(a[kk], sW[kk * 32 + jj], acc2);
        float h = fmaxf(fmaf(di, acc2, sb[jj]), 0.f);
        c = fmaf(h, sf[jj], c);
    }
    int bidx = batch[i];
    int slot = i & (PSPREAD - 1);
    atomicAdd(&pool[slot * G + bidx], c);
    atomicAdd(&gcnt[slot * G + bidx], 1);
}

__global__ void k_out(const float* __restrict__ pool, const int* __restrict__ gcnt,
                      const float* __restrict__ fcb, float* __restrict__ out, int G) {
    int gI = blockIdx.x * blockDim.x + threadIdx.x;
    if (gI >= G) return;
    float s = 0.f; int c = 0;
#pragma unroll
    for (int k = 0; k < PSPREAD; ++k) { s += pool[k * G + gI]; c += gcnt[k * G + gI]; }
    out[gI] = s / fmaxf((float)c, 1.f) + fcb[0];
}

extern "C" void kernel_launch(void* const* d_in, const int* in_sizes, int n_in,
                              void* d_out, int out_size, void* d_ws, size_t ws_size,
                              hipStream_t stream) {
    const float* x    = (const float*)d_in[0];
    const int*   ei   = (const int*)d_in[1];
    const int*   batch= (const int*)d_in[2];
    const float* W1   = (const float*)d_in[3];
    const float* b1   = (const float*)d_in[4];
    const float* W2   = (const float*)d_in[5];
    const float* b2   = (const float*)d_in[6];
    const float* fcW  = (const float*)d_in[7];
    const float* fcb  = (const float*)d_in[8];
    float* out = (float*)d_out;

    const int N = in_sizes[0] / 5;
    const int E = in_sizes[1] / 2;
    const int G = out_size;  // 1024
    const int Nhalf = (N + 1) / 2;

    const int* src = ei;
    const int* dst = ei + E;

    // workspace carve (all offsets 16B-aligned)
    char* ws = (char*)d_ws;
    size_t o = 0;
    int*   bhist  = (int*)  (ws + o); o += 2048;
    int*   bbase  = (int*)  (ws + o); o += 2048;            // NB+1 ints
    int*   bcursor= (int*)  (ws + o); o += 2048;
    int*   rp2    = (int*)  (ws + o); o += (size_t)4 * (NB * NKEY + 4);
    float* dinv   = (float*)(ws + o); o += (size_t)4 * N;
    float* sx8    = (float*)(ws + o); o += (size_t)32 * N;
    float* agg8   = (float*)(ws + o); o += (size_t)32 * N;
    float* agg16  = (float*)(ws + o); o += (size_t)64 * N;
    int*   srt    = (int*)  (ws + o); o += (size_t)4 * E;
    unsigned int* recbuf = (unsigned int*)(ws + o);         // 4E, dead after k_sort
    float* g      = (float*)(ws + o); o += (size_t)4 * E;   // g (64N) aliases recbuf
    float* pool   = (float*)(ws + o); o += (size_t)4 * PSPREAD * G;
    int*   gcnt   = (int*)  (ws + o); o += (size_t)4 * PSPREAD * G;

    hipMemsetAsync(bhist, 0, 2048, stream);
    hipMemsetAsync(pool, 0, (size_t)8 * PSPREAD * G, stream);  // pool+gcnt contiguous

    k_hist<<<256, 256, 0, stream>>>(dst, E, bhist);
    k_scan<<<1, 512, 0, stream>>>(bhist, bbase, bcursor);
    k_bin<<<(E + BINCHUNK - 1) / BINCHUNK, 256, 0, stream>>>(src, dst, bcursor, recbuf, E);
    k_sort<<<NB, 512, 0, stream>>>(bbase, recbuf, rp2, srt, Nhalf);
    k_prep<<<(N + 255) / 256, 256, 0, stream>>>(x, rp2, dinv, sx8, N);
    {
        int blocks = (int)(((long long)N * 64 + 255) / 256);
        k_gather8<<<blocks, 256, 0, stream>>>(rp2, srt, sx8, agg8, N);
    }
    k_lin1<<<(N + 255) / 256, 256, 0, stream>>>(agg8, dinv, W1, b1, g, agg16, N);
    {
        int blocks = (int)(((long long)N * 64 + 255) / 256);
        k_gath16h<<<blocks, 256, 0, stream>>>(rp2, srt, g, agg16, N, 0);
        k_gath16h<<<blocks, 256, 0, stream>>>(rp2, srt, g, agg16, N, RANGE);
    }
    k_fin<<<(N + 255) / 256, 256, 0, stream>>>(agg16, dinv, W2, b2, fcW, batch, pool, gcnt, N, G);
    k_out<<<(G + 255) / 256, 256, 0, stream>>>(pool, gcnt, fcb, out, G);
}

// Round 10
// 292.258 us; speedup vs baseline: 1.2657x; 1.0829x over previous
//
#include <hip/hip_runtime.h>

// GCN: 2x GCNConv (5->16->32) + global mean pool + linear head.
// v9: fixed-capacity dst buckets, 64B-aligned segment allocation in k_bin,
// per-bucket LDS counting sort keyed by (src-half, dst_local), atomic-free
// gather-reduce. Layer-2 aggregation as two passes over 3.2 MB g-halves
// (per-XCD-L2-resident). vs v8: CAP sized for padding waste (v8 overflowed
// ~900 recs/bucket into the neighbor slice -> absmax 2.6e-3), BINCHUNK=16384
// halves segment count, all carves 256B-aligned, late buffers alias recbuf.

#define RANGE 256          // nodes per bucket (d>>8)
#define NB 391             // ceil(100000/256)
#define NKEY 512           // (src-half, dst_local) keys per bucket
#define RPB (NKEY + 1)     // rp2b entries per bucket (incl. end sentinel)
#define CAP 12288          // record capacity per bucket (8192 mean + 10sigma + worst-case pad)
#define BINCHUNK 16384
#define PSPREAD 8
#define SENT 0xFFFFFFFFu

// bin edges into fixed-capacity bucket slices; rec = (src<<8) | dst_local.
// per-(block,bucket) segments are 16-record (64B) aligned; gaps get SENT.
__global__ void k_bin(const int* __restrict__ src, const int* __restrict__ dst,
                      int* __restrict__ bcursor, unsigned int* __restrict__ recbuf, int E) {
    __shared__ int h[NB], h2[NB], base_l[NB];
    for (int t = threadIdx.x; t < NB; t += blockDim.x) { h[t] = 0; h2[t] = 0; }
    __syncthreads();
    int e0 = blockIdx.x * BINCHUNK;
    int e1 = min(e0 + BINCHUNK, E);
    for (int e = e0 + threadIdx.x; e < e1; e += blockDim.x)
        atomicAdd(&h[__builtin_nontemporal_load(dst + e) >> 8], 1);
    __syncthreads();
    for (int t = threadIdx.x; t < NB; t += blockDim.x) {
        int c = h[t];
        if (c) {
            int pad = (c + 15) & ~15;
            int off = atomicAdd(&bcursor[t], pad);
            base_l[t] = off;
            unsigned* gb = recbuf + (size_t)t * CAP + off;
            for (int i = c; i < pad; ++i) gb[i] = SENT;
        }
    }
    __syncthreads();
    for (int e = e0 + threadIdx.x; e < e1; e += blockDim.x) {
        int d = __builtin_nontemporal_load(dst + e);
        int s = __builtin_nontemporal_load(src + e);
        int b = d >> 8;
        int rank = atomicAdd(&h2[b], 1);
        recbuf[(size_t)b * CAP + base_l[b] + rank] = ((unsigned)s << 8) | (unsigned)(d & 255);
    }
}

// per-bucket LDS counting sort, key = (src>=Nhalf)*RANGE + dst_local.
// rp2b[b*RPB + key] = run start; rp2b[b*RPB + NKEY] = bucket end. srt = src.
__global__ __launch_bounds__(512) void k_sort(const int* __restrict__ bcursor,
        const unsigned int* __restrict__ recbuf, int* __restrict__ rp2b,
        int* __restrict__ srt, int Nhalf) {
    __shared__ int cnt[NKEY], lbase[NKEY], rank[NKEY], sc[NKEY];
    int b = blockIdx.x;
    int t = threadIdx.x;
    cnt[t] = 0; rank[t] = 0;
    __syncthreads();
    int len = bcursor[b];
    int g0 = b * CAP;
    const unsigned* rb = recbuf + (size_t)g0;
    for (int r = t; r < len; r += 512) {
        unsigned rec = __builtin_nontemporal_load(rb + r);
        if (rec != SENT) {
            int key = ((int)(rec >> 8) >= Nhalf ? RANGE : 0) + (int)(rec & 255);
            atomicAdd(&cnt[key], 1);
        }
    }
    __syncthreads();
    sc[t] = cnt[t];
    __syncthreads();
    for (int off = 1; off < NKEY; off <<= 1) {
        int u = (t >= off) ? sc[t - off] : 0;
        __syncthreads();
        sc[t] += u;
        __syncthreads();
    }
    lbase[t] = sc[t] - cnt[t];
    rp2b[b * RPB + t] = g0 + lbase[t];
    if (t == NKEY - 1) rp2b[b * RPB + NKEY] = g0 + sc[t];
    __syncthreads();
    for (int r = t; r < len; r += 512) {
        unsigned rec = __builtin_nontemporal_load(rb + r);
        if (rec != SENT) {
            int srcv = (int)(rec >> 8);
            int key = (srcv >= Nhalf ? RANGE : 0) + (int)(rec & 255);
            int pos = g0 + lbase[key] + atomicAdd(&rank[key], 1);
            srt[pos] = srcv;   // plain store: L2-merged within bucket slice
        }
    }
}

// dinv = rsqrt(deg+1) from rp2b; sx8 = [dinv*x (5), 0,0,0]
__global__ void k_prep(const float* __restrict__ x, const int* __restrict__ rp2b,
                       float* __restrict__ dinv, float* __restrict__ sx8, int N) {
    int i = blockIdx.x * blockDim.x + threadIdx.x;
    if (i >= N) return;
    int b = i >> 8, dl = i & 255;
    int base = b * RPB + dl;
    int degA = rp2b[base + 1] - rp2b[base];
    int degB = rp2b[base + RANGE + 1] - rp2b[base + RANGE];
    float di = rsqrtf((float)(degA + degB + 1));
    dinv[i] = di;
    float4 a, bb;
    a.x = x[i * 5 + 0] * di; a.y = x[i * 5 + 1] * di;
    a.z = x[i * 5 + 2] * di; a.w = x[i * 5 + 3] * di;
    bb.x = x[i * 5 + 4] * di; bb.y = 0.f; bb.z = 0.f; bb.w = 0.f;
    float4* p = (float4*)(sx8 + (size_t)i * 8);
    p[0] = a; p[1] = bb;
}

// one wave per node; 8 feature lanes x 8 row slots; walks both A and B runs
__global__ void k_gather8(const int* __restrict__ rp2b, const int* __restrict__ srt,
                          const float* __restrict__ sx8, float* __restrict__ agg8, int N) {
    int wid = (blockIdx.x * blockDim.x + threadIdx.x) >> 6;
    int lane = threadIdx.x & 63;
    if (wid >= N) return;
    int k = lane & 7, j = lane >> 3;
    int b = wid >> 8, dl = wid & 255;
    int base = b * RPB + dl;
    int pA0 = rp2b[base], pA1 = rp2b[base + 1];
    int pB0 = rp2b[base + RANGE], pB1 = rp2b[base + RANGE + 1];
    float acc = 0.f;
    for (int p = pA0 + j; p < pA1; p += 8)
        acc += sx8[(size_t)__builtin_nontemporal_load(srt + p) * 8 + k];
    for (int p = pB0 + j; p < pB1; p += 8)
        acc += sx8[(size_t)__builtin_nontemporal_load(srt + p) * 8 + k];
    acc += __shfl_xor(acc, 8, 64);
    acc += __shfl_xor(acc, 16, 64);
    acc += __shfl_xor(acc, 32, 64);
    if (lane < 8) agg8[(size_t)wid * 8 + k] = acc + sx8[(size_t)wid * 8 + k];
}

// h1 = relu(dinv*(agg8[:5]@W1) + b1); g = dinv*h1 (16); agg16 init = g (self)
__global__ void k_lin1(const float* __restrict__ agg8, const float* __restrict__ dinv,
                       const float* __restrict__ W1, const float* __restrict__ b1,
                       float* __restrict__ g, float* __restrict__ agg16, int N) {
    __shared__ float sW[80], sb[16];
    if (threadIdx.x < 80) sW[threadIdx.x] = W1[threadIdx.x];
    if (threadIdx.x < 16) sb[threadIdx.x] = b1[threadIdx.x];
    __syncthreads();
    int i = blockIdx.x * blockDim.x + threadIdx.x;
    if (i >= N) return;
    float di = dinv[i];
    const float4* a4 = (const float4*)(agg8 + (size_t)i * 8);
    float4 v0 = a4[0], v1 = a4[1];
    float a[5] = {v0.x, v0.y, v0.z, v0.w, v1.x};
    float4* g4 = (float4*)(g + (size_t)i * 16);
    float4* q4 = (float4*)(agg16 + (size_t)i * 16);
#pragma unroll
    for (int q = 0; q < 4; ++q) {
        float4 v;
        float* vp = (float*)&v;
#pragma unroll
        for (int r = 0; r < 4; ++r) {
            int kk = q * 4 + r;
            float h = 0.f;
#pragma unroll
            for (int d = 0; d < 5; ++d) h = fmaf(a[d], sW[d * 16 + kk], h);
            h = fmaxf(fmaf(di, h, sb[kk]), 0.f);
            vp[r] = h * di;
        }
        g4[q] = v;
        q4[q] = v;
    }
}

// one wave per node; 16 feature lanes x 4 row slots; one src-half run
// (hoff = 0 or RANGE); accumulates into agg16 (self-initialized by k_lin1).
__global__ void k_gath16h(const int* __restrict__ rp2b, const int* __restrict__ srt,
                          const float* __restrict__ g, float* __restrict__ agg16,
                          int N, int hoff) {
    int wid = (blockIdx.x * blockDim.x + threadIdx.x) >> 6;
    int lane = threadIdx.x & 63;
    if (wid >= N) return;
    int k = lane & 15, j = lane >> 4;
    int b = wid >> 8, dl = wid & 255;
    int base = b * RPB + hoff + dl;
    int p0 = rp2b[base], p1 = rp2b[base + 1];
    float prev = 0.f;
    if (lane < 16) prev = agg16[(size_t)wid * 16 + k];
    float acc = 0.f;
    int p = p0 + j;
    for (; p + 4 < p1; p += 8) {
        int sA = __builtin_nontemporal_load(srt + p);
        int sB = __builtin_nontemporal_load(srt + p + 4);
        acc += g[(size_t)sA * 16 + k] + g[(size_t)sB * 16 + k];
    }
    for (; p < p1; p += 4) acc += g[(size_t)__builtin_nontemporal_load(srt + p) * 16 + k];
    acc += __shfl_xor(acc, 16, 64);
    acc += __shfl_xor(acc, 32, 64);
    if (lane < 16) agg16[(size_t)wid * 16 + k] = prev + acc;
}

// h2 = relu(dinv*(agg16@W2) + b2); c = h2 . fcW; spread-8 pool atomics
__global__ void k_fin(const float* __restrict__ agg16, const float* __restrict__ dinv,
                      const float* __restrict__ W2, const float* __restrict__ b2,
                      const float* __restrict__ fcW, const int* __restrict__ batch,
                      float* __restrict__ pool, int* __restrict__ gcnt, int N, int G) {
    __shared__ float sW[512], sb[32], sf[32];
    for (int t = threadIdx.x; t < 512; t += blockDim.x) sW[t] = W2[t];
    if (threadIdx.x < 32) {
        sb[threadIdx.x] = b2[threadIdx.x];
        sf[threadIdx.x] = fcW[threadIdx.x];
    }
    __syncthreads();
    int i = blockIdx.x * blockDim.x + threadIdx.x;
    if (i >= N) return;
    float di = dinv[i];
    float a[16];
    const float4* a4 = (const float4*)(agg16 + (size_t)i * 16);
#pragma unroll
    for (int q = 0; q < 4; ++q) {
        float4 v = a4[q];
        a[q * 4 + 0] = v.x; a[q * 4 + 1] = v.y; a[q * 4 + 2] = v.z; a[q * 4 + 3] = v.w;
    }
    float c = 0.f;
#pragma unroll
    for (int jj = 0; jj < 32; ++jj) {
        float acc2 = 0.f;
#pragma unroll
        for (int kk = 0; kk < 16; ++kk) acc2 = fmaf(a[kk], sW[kk * 32 + jj], acc2);
        float h = fmaxf(fmaf(di, acc2, sb[jj]), 0.f);
        c = fmaf(h, sf[jj], c);
    }
    int bidx = batch[i];
    int slot = i & (PSPREAD - 1);
    atomicAdd(&pool[slot * G + bidx], c);
    atomicAdd(&gcnt[slot * G + bidx], 1);
}

__global__ void k_out(const float* __restrict__ pool, const int* __restrict__ gcnt,
                      const float* __restrict__ fcb, float* __restrict__ out, int G) {
    int gI = blockIdx.x * blockDim.x + threadIdx.x;
    if (gI >= G) return;
    float s = 0.f; int c = 0;
#pragma unroll
    for (int k = 0; k < PSPREAD; ++k) { s += pool[k * G + gI]; c += gcnt[k * G + gI]; }
    out[gI] = s / fmaxf((float)c, 1.f) + fcb[0];
}

extern "C" void kernel_launch(void* const* d_in, const int* in_sizes, int n_in,
                              void* d_out, int out_size, void* d_ws, size_t ws_size,
                              hipStream_t stream) {
    const float* x    = (const float*)d_in[0];
    const int*   ei   = (const int*)d_in[1];
    const int*   batch= (const int*)d_in[2];
    const float* W1   = (const float*)d_in[3];
    const float* b1   = (const float*)d_in[4];
    const float* W2   = (const float*)d_in[5];
    const float* b2   = (const float*)d_in[6];
    const float* fcW  = (const float*)d_in[7];
    const float* fcb  = (const float*)d_in[8];
    float* out = (float*)d_out;

    const int N = in_sizes[0] / 5;
    const int E = in_sizes[1] / 2;
    const int G = out_size;  // 1024
    const int Nhalf = (N + 1) / 2;

    const int* src = ei;
    const int* dst = ei + E;

    // workspace carve, every buffer 256B-aligned
    char* ws = (char*)d_ws;
    size_t o = 0;
    auto carve = [&](size_t bytes) -> char* {
        char* p = ws + o;
        o += (bytes + 255) & ~(size_t)255;
        return p;
    };
    int*   bcursor = (int*)carve((size_t)4 * NB);
    int*   rp2b    = (int*)carve((size_t)4 * (NB * RPB + 4));
    float* dinv    = (float*)carve((size_t)4 * N);
    float* agg8    = (float*)carve((size_t)32 * N);
    int*   srt     = (int*)carve((size_t)4 * NB * CAP);          // ~19.2 MB
    char*  rbase   = carve((size_t)4 * NB * CAP);                // ~19.2 MB
    unsigned int* recbuf = (unsigned int*)rbase;                 // dead after k_sort
    float* g       = (float*)rbase;                              // 16N floats (6.4 MB)
    float* agg16   = (float*)rbase + (size_t)16 * N;             // 16N floats
    float* sx8     = (float*)rbase + (size_t)32 * N;             // 8N floats
    float* pool    = (float*)carve((size_t)4 * PSPREAD * G);
    int*   gcnt    = (int*)carve((size_t)4 * PSPREAD * G);

    hipMemsetAsync(bcursor, 0, (size_t)4 * NB, stream);
    hipMemsetAsync(pool, 0, (size_t)4 * PSPREAD * G, stream);
    hipMemsetAsync(gcnt, 0, (size_t)4 * PSPREAD * G, stream);

    k_bin<<<(E + BINCHUNK - 1) / BINCHUNK, 256, 0, stream>>>(src, dst, bcursor, recbuf, E);
    k_sort<<<NB, 512, 0, stream>>>(bcursor, recbuf, rp2b, srt, Nhalf);
    k_prep<<<(N + 255) / 256, 256, 0, stream>>>(x, rp2b, dinv, sx8, N);
    {
        int blocks = (int)(((long long)N * 64 + 255) / 256);
        k_gather8<<<blocks, 256, 0, stream>>>(rp2b, srt, sx8, agg8, N);
    }
    k_lin1<<<(N + 255) / 256, 256, 0, stream>>>(agg8, dinv, W1, b1, g, agg16, N);
    {
        int blocks = (int)(((long long)N * 64 + 255) / 256);
        k_gath16h<<<blocks, 256, 0, stream>>>(rp2b, srt, g, agg16, N, 0);
        k_gath16h<<<blocks, 256, 0, stream>>>(rp2b, srt, g, agg16, N, RANGE);
    }
    k_fin<<<(N + 255) / 256, 256, 0, stream>>>(agg16, dinv, W2, b2, fcW, batch, pool, gcnt, N, G);
    k_out<<<(G + 255) / 256, 256, 0, stream>>>(pool, gcnt, fcb, out, G);
}

// Round 12
// 253.314 us; speedup vs baseline: 1.4602x; 1.1537x over previous
//
#include <hip/hip_runtime.h>

// GCN: 2x GCNConv (5->16->32) + global mean pool + linear head.
// v11: v10 with the aliasing race fixed. sx8 gets its OWN buffer: in v10 it
// aliased recbuf and k_sort's fused prep wrote it while concurrent blocks
// were still reading their recbuf slices -> corrupted records -> OOB crash.
// g/agg16 still alias recbuf (written only by post-k_sort kernels: safe).
// Structure: fixed-capacity dst buckets, 64B-aligned segment binning
// (391 blocks), per-bucket LDS counting sort by dst_local with fused
// dinv/sx8 prep (cnt[] == degree), atomic-free unified gather-reduce.

#define RANGE 256          // nodes per bucket (d>>8)
#define NB 391             // ceil(100000/256)
#define RPB (RANGE + 1)    // rowptr entries per bucket (incl. end)
#define CAP 12288          // record capacity per bucket (fill ~11200 +- 130)
#define BINCHUNK 8192
#define PSPREAD 8
#define SENT 0xFFFFFFFFu

// bin edges into fixed-capacity bucket slices; rec = (src<<8) | dst_local.
// per-(block,bucket) segments are 16-record (64B) aligned; gaps get SENT.
__global__ void k_bin(const int* __restrict__ src, const int* __restrict__ dst,
                      int* __restrict__ bcursor, unsigned int* __restrict__ recbuf, int E) {
    __shared__ int h[NB], h2[NB], base_l[NB];
    for (int t = threadIdx.x; t < NB; t += blockDim.x) { h[t] = 0; h2[t] = 0; }
    __syncthreads();
    int e0 = blockIdx.x * BINCHUNK;
    int e1 = min(e0 + BINCHUNK, E);
    for (int e = e0 + threadIdx.x; e < e1; e += blockDim.x)
        atomicAdd(&h[__builtin_nontemporal_load(dst + e) >> 8], 1);
    __syncthreads();
    for (int t = threadIdx.x; t < NB; t += blockDim.x) {
        int c = h[t];
        if (c) {
            int pad = (c + 15) & ~15;
            int off = atomicAdd(&bcursor[t], pad);
            base_l[t] = off;
            unsigned* gb = recbuf + (size_t)t * CAP + off;
            for (int i = c; i < pad; ++i) gb[i] = SENT;
        }
    }
    __syncthreads();
    for (int e = e0 + threadIdx.x; e < e1; e += blockDim.x) {
        int d = __builtin_nontemporal_load(dst + e);
        int s = __builtin_nontemporal_load(src + e);
        int b = d >> 8;
        int rank = atomicAdd(&h2[b], 1);
        recbuf[(size_t)b * CAP + base_l[b] + rank] = ((unsigned)s << 8) | (unsigned)(d & 255);
    }
}

// per-bucket LDS counting sort by dst_local; cnt[] doubles as degree, so
// dinv and sx8 (= [dinv*x, 0,0,0]) are computed here too (fused prep).
// rowp[b*RPB + dl] = run start; rowp[b*RPB + RANGE] = bucket end. srt = src.
__global__ __launch_bounds__(512) void k_sort(const int* __restrict__ bcursor,
        const unsigned int* __restrict__ recbuf, int* __restrict__ rowp,
        int* __restrict__ srt, const float* __restrict__ x,
        float* __restrict__ dinv, float* __restrict__ sx8, int N) {
    __shared__ int cnt[RANGE], lbase[RANGE], rank[RANGE], sc[RANGE];
    int b = blockIdx.x;
    int t = threadIdx.x;
    if (t < RANGE) { cnt[t] = 0; rank[t] = 0; }
    __syncthreads();
    int len = bcursor[b];
    int g0 = b * CAP;
    const unsigned* rb = recbuf + (size_t)g0;
    for (int r = t; r < len; r += 512) {
        unsigned rec = __builtin_nontemporal_load(rb + r);
        if (rec != SENT) atomicAdd(&cnt[rec & 255], 1);
    }
    __syncthreads();
    if (t < RANGE) sc[t] = cnt[t];
    __syncthreads();
    for (int off = 1; off < RANGE; off <<= 1) {
        int u = 0;
        if (t < RANGE && t >= off) u = sc[t - off];
        __syncthreads();
        if (t < RANGE) sc[t] += u;
        __syncthreads();
    }
    if (t < RANGE) {
        lbase[t] = sc[t] - cnt[t];
        rowp[b * RPB + t] = g0 + lbase[t];
        if (t == RANGE - 1) rowp[b * RPB + RANGE] = g0 + sc[t];
        // fused prep: cnt[t] is the in-degree of node i (sx8 is NOT aliased)
        int i = b * RANGE + t;
        if (i < N) {
            float di = rsqrtf((float)(cnt[t] + 1));
            dinv[i] = di;
            float4 a, bb;
            a.x = x[i * 5 + 0] * di; a.y = x[i * 5 + 1] * di;
            a.z = x[i * 5 + 2] * di; a.w = x[i * 5 + 3] * di;
            bb.x = x[i * 5 + 4] * di; bb.y = 0.f; bb.z = 0.f; bb.w = 0.f;
            float4* p = (float4*)(sx8 + (size_t)i * 8);
            p[0] = a; p[1] = bb;
        }
    }
    __syncthreads();
    for (int r = t; r < len; r += 512) {
        unsigned rec = __builtin_nontemporal_load(rb + r);
        if (rec != SENT) {
            int key = (int)(rec & 255);
            int pos = g0 + lbase[key] + atomicAdd(&rank[key], 1);
            srt[pos] = (int)(rec >> 8);   // plain store: L2-merged in bucket slice
        }
    }
}

// one wave per node; 8 feature lanes x 8 row slots; register accumulation
__global__ void k_gather8(const int* __restrict__ rowp, const int* __restrict__ srt,
                          const float* __restrict__ sx8, float* __restrict__ agg8, int N) {
    int wid = (blockIdx.x * blockDim.x + threadIdx.x) >> 6;
    int lane = threadIdx.x & 63;
    if (wid >= N) return;
    int k = lane & 7, j = lane >> 3;
    int b = wid >> 8, dl = wid & 255;
    int base = b * RPB + dl;
    int p0 = rowp[base], p1 = rowp[base + 1];
    float acc = 0.f;
    int p = p0 + j;
    for (; p + 8 < p1; p += 16) {
        int sA = __builtin_nontemporal_load(srt + p);
        int sB = __builtin_nontemporal_load(srt + p + 8);
        acc += sx8[(size_t)sA * 8 + k] + sx8[(size_t)sB * 8 + k];
    }
    for (; p < p1; p += 8) acc += sx8[(size_t)__builtin_nontemporal_load(srt + p) * 8 + k];
    acc += __shfl_xor(acc, 8, 64);
    acc += __shfl_xor(acc, 16, 64);
    acc += __shfl_xor(acc, 32, 64);
    if (lane < 8) agg8[(size_t)wid * 8 + k] = acc + sx8[(size_t)wid * 8 + k];
}

// h1 = relu(dinv*(agg8[:5]@W1) + b1); g = dinv*h1 (16)
__global__ void k_lin1(const float* __restrict__ agg8, const float* __restrict__ dinv,
                       const float* __restrict__ W1, const float* __restrict__ b1,
                       float* __restrict__ g, int N) {
    __shared__ float sW[80], sb[16];
    if (threadIdx.x < 80) sW[threadIdx.x] = W1[threadIdx.x];
    if (threadIdx.x < 16) sb[threadIdx.x] = b1[threadIdx.x];
    __syncthreads();
    int i = blockIdx.x * blockDim.x + threadIdx.x;
    if (i >= N) return;
    float di = dinv[i];
    const float4* a4 = (const float4*)(agg8 + (size_t)i * 8);
    float4 v0 = a4[0], v1 = a4[1];
    float a[5] = {v0.x, v0.y, v0.z, v0.w, v1.x};
    float4* g4 = (float4*)(g + (size_t)i * 16);
#pragma unroll
    for (int q = 0; q < 4; ++q) {
        float4 v;
        float* vp = (float*)&v;
#pragma unroll
        for (int r = 0; r < 4; ++r) {
            int kk = q * 4 + r;
            float h = 0.f;
#pragma unroll
            for (int d = 0; d < 5; ++d) h = fmaf(a[d], sW[d * 16 + kk], h);
            h = fmaxf(fmaf(di, h, sb[kk]), 0.f);
            vp[r] = h * di;
        }
        g4[q] = v;
    }
}

// one wave per node; 16 feature lanes x 4 row slots; register accumulation
__global__ void k_gather16(const int* __restrict__ rowp, const int* __restrict__ srt,
                           const float* __restrict__ g, float* __restrict__ agg16, int N) {
    int wid = (blockIdx.x * blockDim.x + threadIdx.x) >> 6;
    int lane = threadIdx.x & 63;
    if (wid >= N) return;
    int k = lane & 15, j = lane >> 4;
    int b = wid >> 8, dl = wid & 255;
    int base = b * RPB + dl;
    int p0 = rowp[base], p1 = rowp[base + 1];
    float acc = 0.f;
    int p = p0 + j;
    for (; p + 12 < p1; p += 16) {
        int sA = __builtin_nontemporal_load(srt + p);
        int sB = __builtin_nontemporal_load(srt + p + 4);
        int sC = __builtin_nontemporal_load(srt + p + 8);
        int sD = __builtin_nontemporal_load(srt + p + 12);
        float vA = g[(size_t)sA * 16 + k];
        float vB = g[(size_t)sB * 16 + k];
        float vC = g[(size_t)sC * 16 + k];
        float vD = g[(size_t)sD * 16 + k];
        acc += (vA + vB) + (vC + vD);
    }
    for (; p < p1; p += 4) acc += g[(size_t)__builtin_nontemporal_load(srt + p) * 16 + k];
    acc += __shfl_xor(acc, 16, 64);
    acc += __shfl_xor(acc, 32, 64);
    if (lane < 16) agg16[(size_t)wid * 16 + k] = acc + g[(size_t)wid * 16 + k];
}

// h2 = relu(dinv*(agg16@W2) + b2); c = h2 . fcW; spread-8 pool atomics
__global__ void k_fin(const float* __restrict__ agg16, const float* __restrict__ dinv,
                      const float* __restrict__ W2, const float* __restrict__ b2,
                      const float* __restrict__ fcW, const int* __restrict__ batch,
                      float* __restrict__ pool, int* __restrict__ gcnt, int N, int G) {
    __shared__ float sW[512], sb[32], sf[32];
    for (int t = threadIdx.x; t < 512; t += blockDim.x) sW[t] = W2[t];
    if (threadIdx.x < 32) {
        sb[threadIdx.x] = b2[threadIdx.x];
        sf[threadIdx.x] = fcW[threadIdx.x];
    }
    __syncthreads();
    int i = blockIdx.x * blockDim.x + threadIdx.x;
    if (i >= N) return;
    float di = dinv[i];
    float a[16];
    const float4* a4 = (const float4*)(agg16 + (size_t)i * 16);
#pragma unroll
    for (int q = 0; q < 4; ++q) {
        float4 v = a4[q];
        a[q * 4 + 0] = v.x; a[q * 4 + 1] = v.y; a[q * 4 + 2] = v.z; a[q * 4 + 3] = v.w;
    }
    float c = 0.f;
#pragma unroll
    for (int jj = 0; jj < 32; ++jj) {
        float acc2 = 0.f;
#pragma unroll
        for (int kk = 0; kk < 16; ++kk) acc2 = fmaf(a[kk], sW[kk * 32 + jj], acc2);
        float h = fmaxf(fmaf(di, acc2, sb[jj]), 0.f);
        c = fmaf(h, sf[jj], c);
    }
    int bidx = batch[i];
    int slot = i & (PSPREAD - 1);
    atomicAdd(&pool[slot * G + bidx], c);
    atomicAdd(&gcnt[slot * G + bidx], 1);
}

__global__ void k_out(const float* __restrict__ pool, const int* __restrict__ gcnt,
                      const float* __restrict__ fcb, float* __restrict__ out, int G) {
    int gI = blockIdx.x * blockDim.x + threadIdx.x;
    if (gI >= G) return;
    float s = 0.f; int c = 0;
#pragma unroll
    for (int k = 0; k < PSPREAD; ++k) { s += pool[k * G + gI]; c += gcnt[k * G + gI]; }
    out[gI] = s / fmaxf((float)c, 1.f) + fcb[0];
}

extern "C" void kernel_launch(void* const* d_in, const int* in_sizes, int n_in,
                              void* d_out, int out_size, void* d_ws, size_t ws_size,
                              hipStream_t stream) {
    const float* x    = (const float*)d_in[0];
    const int*   ei   = (const int*)d_in[1];
    const int*   batch= (const int*)d_in[2];
    const float* W1   = (const float*)d_in[3];
    const float* b1   = (const float*)d_in[4];
    const float* W2   = (const float*)d_in[5];
    const float* b2   = (const float*)d_in[6];
    const float* fcW  = (const float*)d_in[7];
    const float* fcb  = (const float*)d_in[8];
    float* out = (float*)d_out;

    const int N = in_sizes[0] / 5;
    const int E = in_sizes[1] / 2;
    const int G = out_size;  // 1024

    const int* src = ei;
    const int* dst = ei + E;

    // workspace carve, every buffer 256B-aligned
    char* ws = (char*)d_ws;
    size_t o = 0;
    auto carve = [&](size_t bytes) -> char* {
        char* p = ws + o;
        o += (bytes + 255) & ~(size_t)255;
        return p;
    };
    int*   bcursor = (int*)carve((size_t)4 * NB);
    int*   rowp    = (int*)carve((size_t)4 * (NB * RPB + 4));
    float* dinv    = (float*)carve((size_t)4 * N);
    float* sx8     = (float*)carve((size_t)32 * N);              // 3.2 MB — OWN buffer (written inside k_sort)
    float* agg8    = (float*)carve((size_t)32 * N);              // 3.2 MB
    int*   srt     = (int*)carve((size_t)4 * NB * CAP);          // 19.2 MB
    char*  rbase   = carve((size_t)4 * NB * CAP);                // 19.2 MB
    unsigned int* recbuf = (unsigned int*)rbase;                 // dead after k_sort
    float* g       = (float*)rbase;                              // 16N floats (6.4 MB), written post-k_sort
    float* agg16   = (float*)rbase + (size_t)16 * N;             // 16N floats (6.4 MB), written post-k_sort
    float* pool    = (float*)carve((size_t)4 * PSPREAD * G);
    int*   gcnt    = (int*)carve((size_t)4 * PSPREAD * G);

    hipMemsetAsync(bcursor, 0, (size_t)4 * NB, stream);
    hipMemsetAsync(pool, 0, (size_t)4 * PSPREAD * G, stream);
    hipMemsetAsync(gcnt, 0, (size_t)4 * PSPREAD * G, stream);

    k_bin<<<(E + BINCHUNK - 1) / BINCHUNK, 256, 0, stream>>>(src, dst, bcursor, recbuf, E);
    k_sort<<<NB, 512, 0, stream>>>(bcursor, recbuf, rowp, srt, x, dinv, sx8, N);
    {
        int blocks = (int)(((long long)N * 64 + 255) / 256);
        k_gather8<<<blocks, 256, 0, stream>>>(rowp, srt, sx8, agg8, N);
    }
    k_lin1<<<(N + 255) / 256, 256, 0, stream>>>(agg8, dinv, W1, b1, g, N);
    {
        int blocks = (int)(((long long)N * 64 + 255) / 256);
        k_gather16<<<blocks, 256, 0, stream>>>(rowp, srt, g, agg16, N);
    }
    k_fin<<<(N + 255) / 256, 256, 0, stream>>>(agg16, dinv, W2, b2, fcW, batch, pool, gcnt, N, G);
    k_out<<<(G + 255) / 256, 256, 0, stream>>>(pool, gcnt, fcb, out, G);
}

// Round 13
// 225.981 us; speedup vs baseline: 1.6369x; 1.1210x over previous
//
#include <hip/hip_runtime.h>

// GCN: 2x GCNConv (5->16->32) + global mean pool + linear head.
// v12: binning via count->scan->scatter with exact per-(block,bucket) offsets:
// no global cursor atomics, no SENT padding, and the edge-pass grids are
// decoupled from the bucket count (NBLK=2048 blocks -> full occupancy; v11's
// k_bin was latency-bound at 13% occupancy, 72us). Then per-bucket LDS
// counting sort by dst_local with fused dinv/sx8 prep, and atomic-free
// unified gather-reduce (gathers measured latency-bound, not table-bound).

#define RANGE 256          // nodes per bucket (d>>8)
#define NB 391             // ceil(100000/256)
#define RPB (RANGE + 1)    // rowptr entries per bucket (incl. end)
#define CAP 12288          // record capacity per bucket (exact fill ~8184+-300)
#define NBLK 2048          // edge-pass blocks (chunk = ceil(E/NBLK))
#define PSPREAD 8

// per-block LDS histogram of dst buckets -> blkcnt[blk][NB] (coalesced row)
__global__ void k_cnt(const int* __restrict__ dst, int E, int chunk,
                      int* __restrict__ blkcnt) {
    __shared__ int h[NB];
    for (int t = threadIdx.x; t < NB; t += blockDim.x) h[t] = 0;
    __syncthreads();
    int e0 = blockIdx.x * chunk;
    int e1 = min(e0 + chunk, E);
    for (int e = e0 + threadIdx.x; e < e1; e += blockDim.x)
        atomicAdd(&h[dst[e] >> 8], 1);
    __syncthreads();
    int* row = blkcnt + (size_t)blockIdx.x * NB;
    for (int t = threadIdx.x; t < NB; t += blockDim.x) row[t] = h[t];
}

// one block per bucket: exclusive scan over the NBLK per-block counts.
// base[b][blk] = b*CAP + prefix; bfill[b] = bucket total.
__global__ __launch_bounds__(512) void k_scanb(const int* __restrict__ blkcnt,
        int* __restrict__ base, int* __restrict__ bfill) {
    __shared__ int part[512];
    int b = blockIdx.x, t = threadIdx.x;
    // thread t owns blocks 4t..4t+3 (column reads, L2-cached)
    int v0 = blkcnt[(size_t)(4 * t + 0) * NB + b];
    int v1 = blkcnt[(size_t)(4 * t + 1) * NB + b];
    int v2 = blkcnt[(size_t)(4 * t + 2) * NB + b];
    int v3 = blkcnt[(size_t)(4 * t + 3) * NB + b];
    int s = v0 + v1 + v2 + v3;
    part[t] = s;
    __syncthreads();
    for (int off = 1; off < 512; off <<= 1) {
        int u = (t >= off) ? part[t - off] : 0;
        __syncthreads();
        part[t] += u;
        __syncthreads();
    }
    int excl = part[t] - s;
    int g0 = b * CAP + excl;
    int4 o;
    o.x = g0; o.y = g0 + v0; o.z = g0 + v0 + v1; o.w = g0 + v0 + v1 + v2;
    ((int4*)(base + (size_t)b * NBLK))[t] = o;   // coalesced row write
    if (t == 511) bfill[b] = part[511];
}

// scatter records at exact offsets; rec = (src<<8) | dst_local
__global__ void k_scat(const int* __restrict__ src, const int* __restrict__ dst,
                       int E, int chunk, const int* __restrict__ base,
                       unsigned int* __restrict__ recbuf) {
    __shared__ int h2[NB], base_l[NB];
    for (int t = threadIdx.x; t < NB; t += blockDim.x) h2[t] = 0;
    __syncthreads();
    for (int t = threadIdx.x; t < NB; t += blockDim.x)
        base_l[t] = base[(size_t)t * NBLK + blockIdx.x];  // column reads, L2-cached
    __syncthreads();
    int e0 = blockIdx.x * chunk;
    int e1 = min(e0 + chunk, E);
    for (int e = e0 + threadIdx.x; e < e1; e += blockDim.x) {
        int d = dst[e];
        int s = src[e];
        int b = d >> 8;
        int rank = atomicAdd(&h2[b], 1);
        recbuf[base_l[b] + rank] = ((unsigned)s << 8) | (unsigned)(d & 255);
    }
}

// per-bucket LDS counting sort by dst_local; cnt[] doubles as degree, so
// dinv and sx8 (= [dinv*x, 0,0,0]) are computed here too (fused prep).
// rowp[b*RPB + dl] = run start; rowp[b*RPB + RANGE] = bucket end. srt = src.
__global__ __launch_bounds__(512) void k_sort(const int* __restrict__ bfill,
        const unsigned int* __restrict__ recbuf, int* __restrict__ rowp,
        int* __restrict__ srt, const float* __restrict__ x,
        float* __restrict__ dinv, float* __restrict__ sx8, int N) {
    __shared__ int cnt[RANGE], lbase[RANGE], rank[RANGE], sc[RANGE];
    int b = blockIdx.x;
    int t = threadIdx.x;
    if (t < RANGE) { cnt[t] = 0; rank[t] = 0; }
    __syncthreads();
    int len = bfill[b];
    int g0 = b * CAP;
    const unsigned* rb = recbuf + (size_t)g0;
    for (int r = t; r < len; r += 512)
        atomicAdd(&cnt[__builtin_nontemporal_load(rb + r) & 255], 1);
    __syncthreads();
    if (t < RANGE) sc[t] = cnt[t];
    __syncthreads();
    for (int off = 1; off < RANGE; off <<= 1) {
        int u = 0;
        if (t < RANGE && t >= off) u = sc[t - off];
        __syncthreads();
        if (t < RANGE) sc[t] += u;
        __syncthreads();
    }
    if (t < RANGE) {
        lbase[t] = sc[t] - cnt[t];
        rowp[b * RPB + t] = g0 + lbase[t];
        if (t == RANGE - 1) rowp[b * RPB + RANGE] = g0 + sc[t];
        // fused prep: cnt[t] is the in-degree of node i
        int i = b * RANGE + t;
        if (i < N) {
            float di = rsqrtf((float)(cnt[t] + 1));
            dinv[i] = di;
            float4 a, bb;
            a.x = x[i * 5 + 0] * di; a.y = x[i * 5 + 1] * di;
            a.z = x[i * 5 + 2] * di; a.w = x[i * 5 + 3] * di;
            bb.x = x[i * 5 + 4] * di; bb.y = 0.f; bb.z = 0.f; bb.w = 0.f;
            float4* p = (float4*)(sx8 + (size_t)i * 8);
            p[0] = a; p[1] = bb;
        }
    }
    __syncthreads();
    for (int r = t; r < len; r += 512) {
        unsigned rec = __builtin_nontemporal_load(rb + r);
        int key = (int)(rec & 255);
        int pos = g0 + lbase[key] + atomicAdd(&rank[key], 1);
        srt[pos] = (int)(rec >> 8);   // plain store: L2-merged in bucket slice
    }
}

// one wave per node; 8 feature lanes x 8 row slots; register accumulation
__global__ void k_gather8(const int* __restrict__ rowp, const int* __restrict__ srt,
                          const float* __restrict__ sx8, float* __restrict__ agg8, int N) {
    int wid = (blockIdx.x * blockDim.x + threadIdx.x) >> 6;
    int lane = threadIdx.x & 63;
    if (wid >= N) return;
    int k = lane & 7, j = lane >> 3;
    int b = wid >> 8, dl = wid & 255;
    int base = b * RPB + dl;
    int p0 = rowp[base], p1 = rowp[base + 1];
    float acc = 0.f;
    int p = p0 + j;
    for (; p + 8 < p1; p += 16) {
        int sA = __builtin_nontemporal_load(srt + p);
        int sB = __builtin_nontemporal_load(srt + p + 8);
        acc += sx8[(size_t)sA * 8 + k] + sx8[(size_t)sB * 8 + k];
    }
    for (; p < p1; p += 8) acc += sx8[(size_t)__builtin_nontemporal_load(srt + p) * 8 + k];
    acc += __shfl_xor(acc, 8, 64);
    acc += __shfl_xor(acc, 16, 64);
    acc += __shfl_xor(acc, 32, 64);
    if (lane < 8) agg8[(size_t)wid * 8 + k] = acc + sx8[(size_t)wid * 8 + k];
}

// h1 = relu(dinv*(agg8[:5]@W1) + b1); g = dinv*h1 (16)
__global__ void k_lin1(const float* __restrict__ agg8, const float* __restrict__ dinv,
                       const float* __restrict__ W1, const float* __restrict__ b1,
                       float* __restrict__ g, int N) {
    __shared__ float sW[80], sb[16];
    if (threadIdx.x < 80) sW[threadIdx.x] = W1[threadIdx.x];
    if (threadIdx.x < 16) sb[threadIdx.x] = b1[threadIdx.x];
    __syncthreads();
    int i = blockIdx.x * blockDim.x + threadIdx.x;
    if (i >= N) return;
    float di = dinv[i];
    const float4* a4 = (const float4*)(agg8 + (size_t)i * 8);
    float4 v0 = a4[0], v1 = a4[1];
    float a[5] = {v0.x, v0.y, v0.z, v0.w, v1.x};
    float4* g4 = (float4*)(g + (size_t)i * 16);
#pragma unroll
    for (int q = 0; q < 4; ++q) {
        float4 v;
        float* vp = (float*)&v;
#pragma unroll
        for (int r = 0; r < 4; ++r) {
            int kk = q * 4 + r;
            float h = 0.f;
#pragma unroll
            for (int d = 0; d < 5; ++d) h = fmaf(a[d], sW[d * 16 + kk], h);
            h = fmaxf(fmaf(di, h, sb[kk]), 0.f);
            vp[r] = h * di;
        }
        g4[q] = v;
    }
}

// one wave per node; 16 feature lanes x 4 row slots; register accumulation
__global__ void k_gather16(const int* __restrict__ rowp, const int* __restrict__ srt,
                           const float* __restrict__ g, float* __restrict__ agg16, int N) {
    int wid = (blockIdx.x * blockDim.x + threadIdx.x) >> 6;
    int lane = threadIdx.x & 63;
    if (wid >= N) return;
    int k = lane & 15, j = lane >> 4;
    int b = wid >> 8, dl = wid & 255;
    int base = b * RPB + dl;
    int p0 = rowp[base], p1 = rowp[base + 1];
    float acc = 0.f;
    int p = p0 + j;
    for (; p + 12 < p1; p += 16) {
        int sA = __builtin_nontemporal_load(srt + p);
        int sB = __builtin_nontemporal_load(srt + p + 4);
        int sC = __builtin_nontemporal_load(srt + p + 8);
        int sD = __builtin_nontemporal_load(srt + p + 12);
        float vA = g[(size_t)sA * 16 + k];
        float vB = g[(size_t)sB * 16 + k];
        float vC = g[(size_t)sC * 16 + k];
        float vD = g[(size_t)sD * 16 + k];
        acc += (vA + vB) + (vC + vD);
    }
    for (; p < p1; p += 4) acc += g[(size_t)__builtin_nontemporal_load(srt + p) * 16 + k];
    acc += __shfl_xor(acc, 16, 64);
    acc += __shfl_xor(acc, 32, 64);
    if (lane < 16) agg16[(size_t)wid * 16 + k] = acc + g[(size_t)wid * 16 + k];
}

// h2 = relu(dinv*(agg16@W2) + b2); c = h2 . fcW; spread-8 pool atomics
__global__ void k_fin(const float* __restrict__ agg16, const float* __restrict__ dinv,
                      const float* __restrict__ W2, const float* __restrict__ b2,
                      const float* __restrict__ fcW, const int* __restrict__ batch,
                      float* __restrict__ pool, int* __restrict__ gcnt, int N, int G) {
    __shared__ float sW[512], sb[32], sf[32];
    for (int t = threadIdx.x; t < 512; t += blockDim.x) sW[t] = W2[t];
    if (threadIdx.x < 32) {
        sb[threadIdx.x] = b2[threadIdx.x];
        sf[threadIdx.x] = fcW[threadIdx.x];
    }
    __syncthreads();
    int i = blockIdx.x * blockDim.x + threadIdx.x;
    if (i >= N) return;
    float di = dinv[i];
    float a[16];
    const float4* a4 = (const float4*)(agg16 + (size_t)i * 16);
#pragma unroll
    for (int q = 0; q < 4; ++q) {
        float4 v = a4[q];
        a[q * 4 + 0] = v.x; a[q * 4 + 1] = v.y; a[q * 4 + 2] = v.z; a[q * 4 + 3] = v.w;
    }
    float c = 0.f;
#pragma unroll
    for (int jj = 0; jj < 32; ++jj) {
        float acc2 = 0.f;
#pragma unroll
        for (int kk = 0; kk < 16; ++kk) acc2 = fmaf(a[kk], sW[kk * 32 + jj], acc2);
        float h = fmaxf(fmaf(di, acc2, sb[jj]), 0.f);
        c = fmaf(h, sf[jj], c);
    }
    int bidx = batch[i];
    int slot = i & (PSPREAD - 1);
    atomicAdd(&pool[slot * G + bidx], c);
    atomicAdd(&gcnt[slot * G + bidx], 1);
}

__global__ void k_out(const float* __restrict__ pool, const int* __restrict__ gcnt,
                      const float* __restrict__ fcb, float* __restrict__ out, int G) {
    int gI = blockIdx.x * blockDim.x + threadIdx.x;
    if (gI >= G) return;
    float s = 0.f; int c = 0;
#pragma unroll
    for (int k = 0; k < PSPREAD; ++k) { s += pool[k * G + gI]; c += gcnt[k * G + gI]; }
    out[gI] = s / fmaxf((float)c, 1.f) + fcb[0];
}

extern "C" void kernel_launch(void* const* d_in, const int* in_sizes, int n_in,
                              void* d_out, int out_size, void* d_ws, size_t ws_size,
                              hipStream_t stream) {
    const float* x    = (const float*)d_in[0];
    const int*   ei   = (const int*)d_in[1];
    const int*   batch= (const int*)d_in[2];
    const float* W1   = (const float*)d_in[3];
    const float* b1   = (const float*)d_in[4];
    const float* W2   = (const float*)d_in[5];
    const float* b2   = (const float*)d_in[6];
    const float* fcW  = (const float*)d_in[7];
    const float* fcb  = (const float*)d_in[8];
    float* out = (float*)d_out;

    const int N = in_sizes[0] / 5;
    const int E = in_sizes[1] / 2;
    const int G = out_size;  // 1024
    const int chunk = (E + NBLK - 1) / NBLK;

    const int* src = ei;
    const int* dst = ei + E;

    // workspace carve, every buffer 256B-aligned
    char* ws = (char*)d_ws;
    size_t o = 0;
    auto carve = [&](size_t bytes) -> char* {
        char* p = ws + o;
        o += (bytes + 255) & ~(size_t)255;
        return p;
    };
    int*   bfill   = (int*)carve((size_t)4 * NB);
    int*   rowp    = (int*)carve((size_t)4 * (NB * RPB + 4));
    float* dinv    = (float*)carve((size_t)4 * N);
    float* sx8     = (float*)carve((size_t)32 * N);              // 3.2 MB (written inside k_sort)
    float* agg8    = (float*)carve((size_t)32 * N);              // 3.2 MB
    int*   srt     = (int*)carve((size_t)4 * NB * CAP);          // 19.2 MB
    char*  rbase   = carve((size_t)4 * NB * CAP);                // 19.2 MB
    // blkcnt/base alias srt (dead before k_sort writes srt)
    int*   blkcnt  = srt;                                        // [NBLK][NB]
    int*   base    = srt + (size_t)NBLK * NB;                    // [NB][NBLK]
    unsigned int* recbuf = (unsigned int*)rbase;                 // dead after k_sort
    float* g       = (float*)rbase;                              // 16N floats, written post-k_sort
    float* agg16   = (float*)rbase + (size_t)16 * N;             // 16N floats, written post-k_sort
    float* pool    = (float*)carve((size_t)4 * PSPREAD * G);
    int*   gcnt    = (int*)carve((size_t)4 * PSPREAD * G);

    hipMemsetAsync(pool, 0, (size_t)4 * PSPREAD * G, stream);
    hipMemsetAsync(gcnt, 0, (size_t)4 * PSPREAD * G, stream);

    k_cnt<<<NBLK, 256, 0, stream>>>(dst, E, chunk, blkcnt);
    k_scanb<<<NB, 512, 0, stream>>>(blkcnt, base, bfill);
    k_scat<<<NBLK, 256, 0, stream>>>(src, dst, E, chunk, base, recbuf);
    k_sort<<<NB, 512, 0, stream>>>(bfill, recbuf, rowp, srt, x, dinv, sx8, N);
    {
        int blocks = (int)(((long long)N * 64 + 255) / 256);
        k_gather8<<<blocks, 256, 0, stream>>>(rowp, srt, sx8, agg8, N);
    }
    k_lin1<<<(N + 255) / 256, 256, 0, stream>>>(agg8, dinv, W1, b1, g, N);
    {
        int blocks = (int)(((long long)N * 64 + 255) / 256);
        k_gather16<<<blocks, 256, 0, stream>>>(rowp, srt, g, agg16, N);
    }
    k_fin<<<(N + 255) / 256, 256, 0, stream>>>(agg16, dinv, W2, b2, fcW, batch, pool, gcnt, N, G);
    k_out<<<(G + 255) / 256, 256, 0, stream>>>(pool, gcnt, fcb, out, G);
}

// Round 14
// 201.869 us; speedup vs baseline: 1.8324x; 1.1194x over previous
//
#include <hip/hip_runtime.h>

// GCN: 2x GCNConv (5->16->32) + global mean pool + linear head.
// v13: v12 with the scatter's write amplification fixed. k_scat stages its
// chunk in LDS (counting-sorted by bucket) and burst-writes each per-bucket
// segment with consecutive lanes: every 64B destination line is written once,
// back-to-back, instead of staying open for the whole kernel across 2048
// blocks (v12: 77.5 MB WRITE for 12.8 MB logical, 66us). NBLK=512 so
// segments are ~16 records. Count->scan->scatter remains exact-offset
// (no global atomics, no sentinels). Sort + gather structure unchanged.

#define RANGE 256          // nodes per bucket (d>>8)
#define NB 391             // ceil(100000/256)
#define RPB (RANGE + 1)    // rowptr entries per bucket (incl. end)
#define CAP 10240          // record capacity per bucket (exact fill ~8184+-90)
#define NBLK 512           // edge-pass blocks
#define CHUNKMAX 6400      // >= ceil(E/NBLK) = 6250
#define PSPREAD 8

// per-block LDS histogram of dst buckets -> blkcnt[blk][NB] (coalesced row)
__global__ void k_cnt(const int* __restrict__ dst, int E, int chunk,
                      int* __restrict__ blkcnt) {
    __shared__ int h[NB];
    for (int t = threadIdx.x; t < NB; t += blockDim.x) h[t] = 0;
    __syncthreads();
    int e0 = blockIdx.x * chunk;
    int e1 = min(e0 + chunk, E);
    for (int e = e0 + threadIdx.x; e < e1; e += blockDim.x)
        atomicAdd(&h[dst[e] >> 8], 1);
    __syncthreads();
    int* row = blkcnt + (size_t)blockIdx.x * NB;
    for (int t = threadIdx.x; t < NB; t += blockDim.x) row[t] = h[t];
}

// one block per bucket: exclusive scan over the NBLK per-block counts.
// base[b][blk] = b*CAP + prefix; bfill[b] = bucket total.
__global__ __launch_bounds__(512) void k_scanb(const int* __restrict__ blkcnt,
        int* __restrict__ base, int* __restrict__ bfill) {
    __shared__ int part[NBLK];
    int b = blockIdx.x, t = threadIdx.x;   // NBLK == 512 threads, 1 block each
    int v = blkcnt[(size_t)t * NB + b];    // column read, L2-cached
    part[t] = v;
    __syncthreads();
    for (int off = 1; off < NBLK; off <<= 1) {
        int u = (t >= off) ? part[t - off] : 0;
        __syncthreads();
        part[t] += u;
        __syncthreads();
    }
    base[(size_t)b * NBLK + t] = b * CAP + part[t] - v;  // coalesced row write
    if (t == NBLK - 1) bfill[b] = part[t];
}

// scatter records at exact offsets, via LDS staging sorted by bucket, then
// burst writes (consecutive lanes -> consecutive addresses per segment).
// rec = (src<<8) | dst_local
__global__ __launch_bounds__(512) void k_scat(const int* __restrict__ src,
        const int* __restrict__ dst, int E, int chunk,
        const int* __restrict__ base, unsigned int* __restrict__ recbuf) {
    __shared__ unsigned int lbuf[CHUNKMAX];
    __shared__ unsigned short bkt[CHUNKMAX];
    __shared__ int h[NB], lsc[NB], h2[NB], base_l[NB];
    __shared__ int sc[512];
    int t = threadIdx.x;
    if (t < NB) { h[t] = 0; h2[t] = 0; }
    __syncthreads();
    int e0 = blockIdx.x * chunk;
    int e1 = min(e0 + chunk, E);
    int len = e1 - e0;
    for (int e = e0 + t; e < e1; e += 512)
        atomicAdd(&h[__builtin_nontemporal_load(dst + e) >> 8], 1);
    __syncthreads();
    int v = (t < NB) ? h[t] : 0;
    sc[t] = v;
    __syncthreads();
    for (int off = 1; off < 512; off <<= 1) {
        int u = (t >= off) ? sc[t - off] : 0;
        __syncthreads();
        sc[t] += u;
        __syncthreads();
    }
    if (t < NB) {
        lsc[t] = sc[t] - v;
        base_l[t] = base[(size_t)t * NBLK + blockIdx.x];  // column read, L2-cached
    }
    __syncthreads();
    for (int e = e0 + t; e < e1; e += 512) {
        int d = __builtin_nontemporal_load(dst + e);
        int s = __builtin_nontemporal_load(src + e);
        int b = d >> 8;
        int r = atomicAdd(&h2[b], 1);
        int pos = lsc[b] + r;
        lbuf[pos] = ((unsigned)s << 8) | (unsigned)(d & 255);
        bkt[pos] = (unsigned short)b;
    }
    __syncthreads();
    for (int i = t; i < len; i += 512) {
        int b = bkt[i];
        recbuf[base_l[b] + (i - lsc[b])] = lbuf[i];  // burst per segment
    }
}

// per-bucket LDS counting sort by dst_local; cnt[] doubles as degree, so
// dinv and sx8 (= [dinv*x, 0,0,0]) are computed here too (fused prep).
// rowp[b*RPB + dl] = run start; rowp[b*RPB + RANGE] = bucket end. srt = src.
__global__ __launch_bounds__(512) void k_sort(const int* __restrict__ bfill,
        const unsigned int* __restrict__ recbuf, int* __restrict__ rowp,
        int* __restrict__ srt, const float* __restrict__ x,
        float* __restrict__ dinv, float* __restrict__ sx8, int N) {
    __shared__ int cnt[RANGE], lbase[RANGE], rank[RANGE], sc[RANGE];
    int b = blockIdx.x;
    int t = threadIdx.x;
    if (t < RANGE) { cnt[t] = 0; rank[t] = 0; }
    __syncthreads();
    int len = bfill[b];
    int g0 = b * CAP;
    const unsigned* rb = recbuf + (size_t)g0;
    for (int r = t; r < len; r += 512)
        atomicAdd(&cnt[__builtin_nontemporal_load(rb + r) & 255], 1);
    __syncthreads();
    if (t < RANGE) sc[t] = cnt[t];
    __syncthreads();
    for (int off = 1; off < RANGE; off <<= 1) {
        int u = 0;
        if (t < RANGE && t >= off) u = sc[t - off];
        __syncthreads();
        if (t < RANGE) sc[t] += u;
        __syncthreads();
    }
    if (t < RANGE) {
        lbase[t] = sc[t] - cnt[t];
        rowp[b * RPB + t] = g0 + lbase[t];
        if (t == RANGE - 1) rowp[b * RPB + RANGE] = g0 + sc[t];
        // fused prep: cnt[t] is the in-degree of node i
        int i = b * RANGE + t;
        if (i < N) {
            float di = rsqrtf((float)(cnt[t] + 1));
            dinv[i] = di;
            float4 a, bb;
            a.x = x[i * 5 + 0] * di; a.y = x[i * 5 + 1] * di;
            a.z = x[i * 5 + 2] * di; a.w = x[i * 5 + 3] * di;
            bb.x = x[i * 5 + 4] * di; bb.y = 0.f; bb.z = 0.f; bb.w = 0.f;
            float4* p = (float4*)(sx8 + (size_t)i * 8);
            p[0] = a; p[1] = bb;
        }
    }
    __syncthreads();
    for (int r = t; r < len; r += 512) {
        unsigned rec = __builtin_nontemporal_load(rb + r);
        int key = (int)(rec & 255);
        int pos = g0 + lbase[key] + atomicAdd(&rank[key], 1);
        srt[pos] = (int)(rec >> 8);   // plain store: L2-merged in bucket slice
    }
}

// one wave per node; 8 feature lanes x 8 row slots; register accumulation
__global__ void k_gather8(const int* __restrict__ rowp, const int* __restrict__ srt,
                          const float* __restrict__ sx8, float* __restrict__ agg8, int N) {
    int wid = (blockIdx.x * blockDim.x + threadIdx.x) >> 6;
    int lane = threadIdx.x & 63;
    if (wid >= N) return;
    int k = lane & 7, j = lane >> 3;
    int b = wid >> 8, dl = wid & 255;
    int base = b * RPB + dl;
    int p0 = rowp[base], p1 = rowp[base + 1];
    float acc = 0.f;
    int p = p0 + j;
    for (; p + 8 < p1; p += 16) {
        int sA = __builtin_nontemporal_load(srt + p);
        int sB = __builtin_nontemporal_load(srt + p + 8);
        acc += sx8[(size_t)sA * 8 + k] + sx8[(size_t)sB * 8 + k];
    }
    for (; p < p1; p += 8) acc += sx8[(size_t)__builtin_nontemporal_load(srt + p) * 8 + k];
    acc += __shfl_xor(acc, 8, 64);
    acc += __shfl_xor(acc, 16, 64);
    acc += __shfl_xor(acc, 32, 64);
    if (lane < 8) agg8[(size_t)wid * 8 + k] = acc + sx8[(size_t)wid * 8 + k];
}

// h1 = relu(dinv*(agg8[:5]@W1) + b1); g = dinv*h1 (16)
__global__ void k_lin1(const float* __restrict__ agg8, const float* __restrict__ dinv,
                       const float* __restrict__ W1, const float* __restrict__ b1,
                       float* __restrict__ g, int N) {
    __shared__ float sW[80], sb[16];
    if (threadIdx.x < 80) sW[threadIdx.x] = W1[threadIdx.x];
    if (threadIdx.x < 16) sb[threadIdx.x] = b1[threadIdx.x];
    __syncthreads();
    int i = blockIdx.x * blockDim.x + threadIdx.x;
    if (i >= N) return;
    float di = dinv[i];
    const float4* a4 = (const float4*)(agg8 + (size_t)i * 8);
    float4 v0 = a4[0], v1 = a4[1];
    float a[5] = {v0.x, v0.y, v0.z, v0.w, v1.x};
    float4* g4 = (float4*)(g + (size_t)i * 16);
#pragma unroll
    for (int q = 0; q < 4; ++q) {
        float4 v;
        float* vp = (float*)&v;
#pragma unroll
        for (int r = 0; r < 4; ++r) {
            int kk = q * 4 + r;
            float h = 0.f;
#pragma unroll
            for (int d = 0; d < 5; ++d) h = fmaf(a[d], sW[d * 16 + kk], h);
            h = fmaxf(fmaf(di, h, sb[kk]), 0.f);
            vp[r] = h * di;
        }
        g4[q] = v;
    }
}

// one wave per node; 16 feature lanes x 4 row slots; register accumulation
__global__ void k_gather16(const int* __restrict__ rowp, const int* __restrict__ srt,
                           const float* __restrict__ g, float* __restrict__ agg16, int N) {
    int wid = (blockIdx.x * blockDim.x + threadIdx.x) >> 6;
    int lane = threadIdx.x & 63;
    if (wid >= N) return;
    int k = lane & 15, j = lane >> 4;
    int b = wid >> 8, dl = wid & 255;
    int base = b * RPB + dl;
    int p0 = rowp[base], p1 = rowp[base + 1];
    float acc = 0.f;
    int p = p0 + j;
    for (; p + 12 < p1; p += 16) {
        int sA = __builtin_nontemporal_load(srt + p);
        int sB = __builtin_nontemporal_load(srt + p + 4);
        int sC = __builtin_nontemporal_load(srt + p + 8);
        int sD = __builtin_nontemporal_load(srt + p + 12);
        float vA = g[(size_t)sA * 16 + k];
        float vB = g[(size_t)sB * 16 + k];
        float vC = g[(size_t)sC * 16 + k];
        float vD = g[(size_t)sD * 16 + k];
        acc += (vA + vB) + (vC + vD);
    }
    for (; p < p1; p += 4) acc += g[(size_t)__builtin_nontemporal_load(srt + p) * 16 + k];
    acc += __shfl_xor(acc, 16, 64);
    acc += __shfl_xor(acc, 32, 64);
    if (lane < 16) agg16[(size_t)wid * 16 + k] = acc + g[(size_t)wid * 16 + k];
}

// h2 = relu(dinv*(agg16@W2) + b2); c = h2 . fcW; spread-8 pool atomics
__global__ void k_fin(const float* __restrict__ agg16, const float* __restrict__ dinv,
                      const float* __restrict__ W2, const float* __restrict__ b2,
                      const float* __restrict__ fcW, const int* __restrict__ batch,
                      float* __restrict__ pool, int* __restrict__ gcnt, int N, int G) {
    __shared__ float sW[512], sb[32], sf[32];
    for (int t = threadIdx.x; t < 512; t += blockDim.x) sW[t] = W2[t];
    if (threadIdx.x < 32) {
        sb[threadIdx.x] = b2[threadIdx.x];
        sf[threadIdx.x] = fcW[threadIdx.x];
    }
    __syncthreads();
    int i = blockIdx.x * blockDim.x + threadIdx.x;
    if (i >= N) return;
    float di = dinv[i];
    float a[16];
    const float4* a4 = (const float4*)(agg16 + (size_t)i * 16);
#pragma unroll
    for (int q = 0; q < 4; ++q) {
        float4 v = a4[q];
        a[q * 4 + 0] = v.x; a[q * 4 + 1] = v.y; a[q * 4 + 2] = v.z; a[q * 4 + 3] = v.w;
    }
    float c = 0.f;
#pragma unroll
    for (int jj = 0; jj < 32; ++jj) {
        float acc2 = 0.f;
#pragma unroll
        for (int kk = 0; kk < 16; ++kk) acc2 = fmaf(a[kk], sW[kk * 32 + jj], acc2);
        float h = fmaxf(fmaf(di, acc2, sb[jj]), 0.f);
        c = fmaf(h, sf[jj], c);
    }
    int bidx = batch[i];
    int slot = i & (PSPREAD - 1);
    atomicAdd(&pool[slot * G + bidx], c);
    atomicAdd(&gcnt[slot * G + bidx], 1);
}

__global__ void k_out(const float* __restrict__ pool, const int* __restrict__ gcnt,
                      const float* __restrict__ fcb, float* __restrict__ out, int G) {
    int gI = blockIdx.x * blockDim.x + threadIdx.x;
    if (gI >= G) return;
    float s = 0.f; int c = 0;
#pragma unroll
    for (int k = 0; k < PSPREAD; ++k) { s += pool[k * G + gI]; c += gcnt[k * G + gI]; }
    out[gI] = s / fmaxf((float)c, 1.f) + fcb[0];
}

extern "C" void kernel_launch(void* const* d_in, const int* in_sizes, int n_in,
                              void* d_out, int out_size, void* d_ws, size_t ws_size,
                              hipStream_t stream) {
    const float* x    = (const float*)d_in[0];
    const int*   ei   = (const int*)d_in[1];
    const int*   batch= (const int*)d_in[2];
    const float* W1   = (const float*)d_in[3];
    const float* b1   = (const float*)d_in[4];
    const float* W2   = (const float*)d_in[5];
    const float* b2   = (const float*)d_in[6];
    const float* fcW  = (const float*)d_in[7];
    const float* fcb  = (const float*)d_in[8];
    float* out = (float*)d_out;

    const int N = in_sizes[0] / 5;
    const int E = in_sizes[1] / 2;
    const int G = out_size;  // 1024
    const int chunk = (E + NBLK - 1) / NBLK;  // 6250 <= CHUNKMAX

    const int* src = ei;
    const int* dst = ei + E;

    // workspace carve, every buffer 256B-aligned
    char* ws = (char*)d_ws;
    size_t o = 0;
    auto carve = [&](size_t bytes) -> char* {
        char* p = ws + o;
        o += (bytes + 255) & ~(size_t)255;
        return p;
    };
    int*   bfill   = (int*)carve((size_t)4 * NB);
    int*   rowp    = (int*)carve((size_t)4 * (NB * RPB + 4));
    float* dinv    = (float*)carve((size_t)4 * N);
    float* sx8     = (float*)carve((size_t)32 * N);              // 3.2 MB (written inside k_sort)
    float* agg8    = (float*)carve((size_t)32 * N);              // 3.2 MB
    int*   srt     = (int*)carve((size_t)4 * NB * CAP);          // 16 MB
    char*  rbase   = carve((size_t)4 * NB * CAP);                // 16 MB
    // blkcnt/base alias srt (dead before k_sort writes srt)
    int*   blkcnt  = srt;                                        // [NBLK][NB]
    int*   base    = srt + (size_t)NBLK * NB;                    // [NB][NBLK]
    unsigned int* recbuf = (unsigned int*)rbase;                 // dead after k_sort
    float* g       = (float*)rbase;                              // 16N floats, written post-k_sort
    float* agg16   = (float*)rbase + (size_t)16 * N;             // 16N floats, written post-k_sort
    float* pool    = (float*)carve((size_t)4 * PSPREAD * G);
    int*   gcnt    = (int*)carve((size_t)4 * PSPREAD * G);

    hipMemsetAsync(pool, 0, (size_t)4 * PSPREAD * G, stream);
    hipMemsetAsync(gcnt, 0, (size_t)4 * PSPREAD * G, stream);

    k_cnt<<<NBLK, 256, 0, stream>>>(dst, E, chunk, blkcnt);
    k_scanb<<<NB, 512, 0, stream>>>(blkcnt, base, bfill);
    k_scat<<<NBLK, 512, 0, stream>>>(src, dst, E, chunk, base, recbuf);
    k_sort<<<NB, 512, 0, stream>>>(bfill, recbuf, rowp, srt, x, dinv, sx8, N);
    {
        int blocks = (int)(((long long)N * 64 + 255) / 256);
        k_gather8<<<blocks, 256, 0, stream>>>(rowp, srt, sx8, agg8, N);
    }
    k_lin1<<<(N + 255) / 256, 256, 0, stream>>>(agg8, dinv, W1, b1, g, N);
    {
        int blocks = (int)(((long long)N * 64 + 255) / 256);
        k_gather16<<<blocks, 256, 0, stream>>>(rowp, srt, g, agg16, N);
    }
    k_fin<<<(N + 255) / 256, 256, 0, stream>>>(agg16, dinv, W2, b2, fcW, batch, pool, gcnt, N, G);
    k_out<<<(G + 255) / 256, 256, 0, stream>>>(pool, gcnt, fcb, out, G);
}